// Round 4
// baseline (178.246 us; speedup 1.0000x reference)
//
#include <hip/hip_runtime.h>
#include <math.h>

#define BI 64
#define RR 36
#define BC 64
#define WW 50
#define DD 512
#define HH 256
#define CST 132

typedef _Float16 f16x8 __attribute__((ext_vector_type(8)));
typedef _Float16 f16x4 __attribute__((ext_vector_type(4)));
typedef float    f32x4 __attribute__((ext_vector_type(4)));
typedef float    f32x16 __attribute__((ext_vector_type(16)));

__device__ __forceinline__ float wave_sum(float v){
  #pragma unroll
  for (int off=32; off>0; off>>=1) v += __shfl_xor(v, off, 64);
  return v;
}
__device__ __forceinline__ float wave_max(float v){
  #pragma unroll
  for (int off=32; off>0; off>>=1) v = fmaxf(v, __shfl_xor(v, off, 64));
  return v;
}

// async global->LDS DMA, 16B per lane (verified round-3).
__device__ __forceinline__ void gl_lds16(const _Float16* g, _Float16* l){
  __builtin_amdgcn_global_load_lds(
      (const __attribute__((address_space(1))) unsigned int*)g,
      (__attribute__((address_space(3))) unsigned int*)l, 16, 0, 0);
}

// ---------------------------------------------------------------------------
// PrepGram (round-4: 32-row fragment layout for 32x32x16 MFMA).
//  Frag storage: frag = t32*32 + kk (t32 = 32-row tile, kk = 16-col K slice);
//  element (m,k): lane = (m&31) | (((k>>3)&1)<<5), j = k&7,
//  at base + (frag*64 + lane)*8 + j.  Sizes/offsets identical to old layout.
//  bx < 1504 : A (576 blk) + B (928 blk) split producers.
//  bx >= 1504: gram body — fp32 G + f16 B-frag Gfrag (unchanged, 16x16 path).
// ---------------------------------------------------------------------------
__global__ __launch_bounds__(256) void prepgram_kernel(
    const float* __restrict__ imgs, const float* __restrict__ caps,
    const float* __restrict__ sw1, const float* __restrict__ hw1,
    _Float16* __restrict__ Ah, _Float16* __restrict__ Al,
    _Float16* __restrict__ Bh, _Float16* __restrict__ Bl,
    float* __restrict__ G, _Float16* __restrict__ Gfrag)
{
  __shared__ __align__(16) float smem[WW*CST + 1024];   // gram branch only
  if (blockIdx.x < 1504){
    int u = blockIdx.x*256 + threadIdx.x;
    _Float16 *dh, *dl; int idx;
    if (u < 144*1024){ idx = u;            dh = Ah; dl = Al; }
    else             { idx = u - 144*1024; dh = Bh; dl = Bl; }
    const int frag = idx >> 6, lane = idx & 63;
    const int t32 = frag >> 5, kk = frag & 31;
    const int k0 = kk*16 + (lane >> 5)*8;
    f16x8 hv, lv;
    if (u < 144*1024 || t32 < 100){
      const float* src = (u < 144*1024) ? imgs : caps;
      const int m = t32*32 + (lane & 31);
      const float* p = src + (size_t)m*DD + k0;
      #pragma unroll
      for (int j=0;j<8;j++){
        float a = p[j];
        _Float16 h = (_Float16)a;
        hv[j] = h;
        lv[j] = (_Float16)((a - (float)h) * 2048.0f);
      }
    } else {
      const int n = (t32-100)*32 + (lane & 31);           // 0..511
      const float* src = (n < HH) ? (sw1 + n) : (hw1 + n - HH);
      #pragma unroll
      for (int j=0;j<8;j++){
        float a = src[(size_t)(k0+j)*HH];
        _Float16 h = (_Float16)a;
        hv[j] = h;
        lv[j] = (_Float16)((a - (float)h) * 2048.0f);
      }
    }
    *(f16x8*)(dh + (size_t)idx*8) = hv;
    *(f16x8*)(dl + (size_t)idx*8) = lv;
  } else {
    float* cs = smem;
    float* Gt = smem + WW*CST;
    const int bxg  = blockIdx.x - 1504;
    const int c    = bxg >> 2;
    const int tile = bxg & 3;
    const int w0   = tile*16;
    const int nw   = (tile==3) ? 2 : 16;
    const int t=threadIdx.x, lane=t&63, wv=t>>6;
    const int wl = lane < WW ? lane : WW-1;
    float acc[4]={0.f,0.f,0.f,0.f};
    for (int k0=0;k0<DD;k0+=128){
      __syncthreads();
      for (int n=t;n<WW*32;n+=256){
        int row=n>>5, c4=(n&31)*4;
        *(float4*)&cs[row*CST+c4] = *(const float4*)(caps + ((size_t)c*WW+row)*DD + k0 + c4);
      }
      __syncthreads();
      for (int k=0;k<128;k+=4){
        float4 cv = *(const float4*)&cs[wl*CST+k];
        #pragma unroll
        for (int q=0;q<4;q++){
          int lw = wv + q*4;
          if (lw < nw){
            float4 bv = *(const float4*)&cs[(w0+lw)*CST+k];
            acc[q]=fmaf(bv.x,cv.x,acc[q]); acc[q]=fmaf(bv.y,cv.y,acc[q]);
            acc[q]=fmaf(bv.z,cv.z,acc[q]); acc[q]=fmaf(bv.w,cv.w,acc[q]);
          }
        }
      }
    }
    for (int n=t;n<1024;n+=256) Gt[n]=0.f;
    __syncthreads();
    if (lane < WW){
      #pragma unroll
      for (int q=0;q<4;q++){
        int lw = wv + q*4;
        if (lw < nw){
          G[(size_t)c*WW*WW + (w0+lw)*WW + lane] = acc[q];
          Gt[lw*64 + lane] = acc[q];
        }
      }
    }
    __syncthreads();
    {
      int flat = t*4;
      int ks = flat>>9, L=(flat>>3)&63, j0=flat&7;
      const bool ones = (tile==3) && ((L&15)==2);   // frag n == 50
      f16x4 v;
      #pragma unroll
      for (int e=0;e<4;e++)
        v[e] = ones ? (_Float16)1.0f
                    : (_Float16)Gt[(L&15)*64 + ks*32 + ((L>>4)<<3) + j0 + e];
      *(f16x4*)&Gfrag[(size_t)c*4096 + (tile*2+ks)*512 + L*8 + j0] = v;
    }
  }
}

// ---------------------------------------------------------------------------
// Combined S-GEMM + gate-GEMM (round-4): 32x32x16 MFMA, K16 phases.
//  sgemm body: 4 x 16KB LDS buffers, prefetch depth 3, counted vmcnt(8)
//  (never drained to 0 in the main loop), raw s_barrier. Per phase per wave:
//  4 DMA + 8 ds_read_b128 + 12 MFMA.
//  hgate body: 2 x 24KB buffers (2 K16 slices per step), simple drain.
// ---------------------------------------------------------------------------
__global__ __launch_bounds__(256, 2) void sgemm_hgate_kernel(
    const _Float16* __restrict__ Ah, const _Float16* __restrict__ Al,
    const _Float16* __restrict__ Bh, const _Float16* __restrict__ Bl,
    float* __restrict__ Sp,
    const float* __restrict__ imgs,
    const float* __restrict__ sb1, const float* __restrict__ hb1,
    const float* __restrict__ sw2, const float* __restrict__ hw2,
    float* __restrict__ drawS, float* __restrict__ drawH,
    float* __restrict__ rnraw)
{
  __shared__ _Float16 lds[4*8192];
  const int t = threadIdx.x, lane = t & 63, wv = t >> 6;

  if (blockIdx.x >= 36){
    // ---------------- sgemm body ----------------
    const int bx = blockIdx.x - 36;
    const int mb = bx % 18, nb = bx / 18;
    const int wm = wv & 1, wn = wv >> 1;

    f32x16 P[2][2], Q[2][2];
    #pragma unroll
    for (int a=0;a<2;a++)
      #pragma unroll
      for (int b=0;b<2;b++){
        #pragma unroll
        for (int e=0;e<16;e++){ P[a][b][e]=0.f; Q[a][b][e]=0.f; }
      }

    const _Float16* mybase = (wv==0)?Ah:(wv==1)?Al:(wv==2)?Bh:Bl;
    const size_t fb4 = (size_t)((wv<2)? mb : nb)*4;   // first 32-row tile

    // buffer layout (f16 units): u*512, u = wv*4+s: 0-3 Ah, 4-7 Al, 8-11 Bh,
    // 12-15 Bl; sub s = 32-row tile index within the 128-row/col block.
    auto sg_stage = [&](int kk, int bufi){
      _Float16* dstb = lds + bufi*8192 + (wv*4)*512;
      const _Float16* sp_ = mybase + ((fb4*32 + (size_t)kk)*64 + lane)*8;
      #pragma unroll
      for (int s=0;s<4;s++)
        gl_lds16(sp_ + (size_t)s*16384, dstb + s*512);
    };
    auto sg_compute = [&](int bufi){
      const _Float16* L = lds + bufi*8192;
      f16x8 a_h[2], a_l[2], b_h[2], b_l[2];
      #pragma unroll
      for (int rb=0;rb<2;rb++){
        a_h[rb] = *(const f16x8*)&L[(     wm*2+rb)*512 + lane*8];
        a_l[rb] = *(const f16x8*)&L[( 4 + wm*2+rb)*512 + lane*8];
      }
      #pragma unroll
      for (int cb=0;cb<2;cb++){
        b_h[cb] = *(const f16x8*)&L[( 8 + wn*2+cb)*512 + lane*8];
        b_l[cb] = *(const f16x8*)&L[(12 + wn*2+cb)*512 + lane*8];
      }
      asm volatile("s_waitcnt lgkmcnt(0)" ::: "memory");
      __builtin_amdgcn_sched_barrier(0);
      #pragma unroll
      for (int rb=0;rb<2;rb++)
        #pragma unroll
        for (int cb=0;cb<2;cb++){
          P[rb][cb] = __builtin_amdgcn_mfma_f32_32x32x16_f16(a_h[rb], b_h[cb], P[rb][cb],0,0,0);
          Q[rb][cb] = __builtin_amdgcn_mfma_f32_32x32x16_f16(a_h[rb], b_l[cb], Q[rb][cb],0,0,0);
          Q[rb][cb] = __builtin_amdgcn_mfma_f32_32x32x16_f16(a_l[rb], b_h[cb], Q[rb][cb],0,0,0);
        }
    };

    // prologue: 3 phases in flight
    sg_stage(0,0); sg_stage(1,1); sg_stage(2,2);

    for (int kk=0; kk<30; kk++){
      asm volatile("s_waitcnt vmcnt(8)" ::: "memory");   // phase kk landed
      __builtin_amdgcn_s_barrier();                      // all waves' too
      asm volatile("" ::: "memory");
      if (kk < 29) sg_stage(kk+3, (kk+3)&3);
      sg_compute(kk&3);
    }
    asm volatile("s_waitcnt vmcnt(4)" ::: "memory");
    __builtin_amdgcn_s_barrier();
    asm volatile("" ::: "memory");
    sg_compute(30&3);
    asm volatile("s_waitcnt vmcnt(0)" ::: "memory");
    __builtin_amdgcn_s_barrier();
    asm volatile("" ::: "memory");
    sg_compute(31&3);

    // epilogue: C layout col=lane&31, row=(reg&3)+8*(reg>>2)+4*(lane>>5)
    const unsigned colbase = (unsigned)(nb*128 + wn*64 + (lane&31));
    unsigned pc[2];
    #pragma unroll
    for (int cb=0;cb<2;cb++){
      unsigned col = colbase + cb*32;
      unsigned cc = col / 50u, w = col - cc*50u;
      pc[cb] = cc*1800u + w;
    }
    const unsigned rowbase = (unsigned)(mb*128 + wm*64 + ((lane>>5)<<2));
    #pragma unroll
    for (int rb=0;rb<2;rb++)
      #pragma unroll
      for (int reg=0;reg<16;reg++){
        unsigned row = rowbase + rb*32 + (reg&3) + 8*(reg>>2);
        unsigned i = row / 36u, rr_ = row - i*36u;
        size_t pr = (size_t)i*115200u + (size_t)rr_*50u;
        #pragma unroll
        for (int cb=0;cb<2;cb++)
          Sp[pr + pc[cb]] = P[rb][cb][reg] + Q[rb][cb][reg]*(1.0f/2048.0f);
      }
    return;
  }

  // ---------------- hgate body ----------------
  const int mb = blockIdx.x >> 1;
  const int br = blockIdx.x & 1;          // 0 = soft, 1 = hard
  const int wm = wv & 1, wn = wv >> 1;

  f32x16 Acc[2][4];
  #pragma unroll
  for (int a=0;a<2;a++)
    #pragma unroll
    for (int b=0;b<4;b++){
      #pragma unroll
      for (int e=0;e<16;e++) Acc[a][b][e]=0.f;
    }

  // per step (K32 = 2 K16 halves): 24 units: h*12 + uu, uu<4: A t32 mb*4+uu,
  // uu>=4: B t32 100+br*8+(uu-4).  Buffer = 12288 f16 (24 KB), 2 buffers.
  auto hg_stage = [&](int ks, int bufi){
    #pragma unroll
    for (int s=0;s<6;s++){
      const int u = wv*6 + s;
      const int h = (u >= 12) ? 1 : 0, uu = u - h*12;
      const size_t frag = (uu < 4)
        ? (size_t)((mb*4 + uu)*32 + ks*2 + h)
        : (size_t)((100 + br*8 + (uu-4))*32 + ks*2 + h);
      const _Float16* src = ((uu < 4) ? Ah : Bh) + (frag*64 + lane)*8;
      gl_lds16(src, lds + bufi*12288 + h*6144 + uu*512);
    }
  };
  auto hg_compute = [&](int bufi){
    const _Float16* Lb = lds + bufi*12288;
    #pragma unroll
    for (int h=0;h<2;h++){
      f16x8 a[2], b[4];
      #pragma unroll
      for (int rb=0;rb<2;rb++)
        a[rb] = *(const f16x8*)&Lb[h*6144 + (wm*2+rb)*512 + lane*8];
      #pragma unroll
      for (int cb=0;cb<4;cb++)
        b[cb] = *(const f16x8*)&Lb[h*6144 + (4 + wn*4 + cb)*512 + lane*8];
      #pragma unroll
      for (int rb=0;rb<2;rb++)
        #pragma unroll
        for (int cb=0;cb<4;cb++)
          Acc[rb][cb] = __builtin_amdgcn_mfma_f32_32x32x16_f16(a[rb], b[cb], Acc[rb][cb],0,0,0);
    }
  };

  hg_stage(0,0);
  __syncthreads();
  for (int ks=0; ks<16; ks++){
    if (ks < 15) hg_stage(ks+1, (ks+1)&1);
    hg_compute(ks&1);
    __syncthreads();   // drains stage DMAs + retires this buffer's reads
  }

  // gate epilogue: bias+relu+w2, reduce over 256 cols -> raw row sums.
  const float* b1 = br ? hb1 : sb1;
  const float* w2 = br ? hw2 : sw2;
  float bvv[4], wvv[4];
  #pragma unroll
  for (int cb=0;cb<4;cb++){
    const int col = wn*128 + cb*32 + (lane&31);
    bvv[cb] = b1[col]; wvv[cb] = w2[col];
  }
  float* red = (float*)lds;
  #pragma unroll
  for (int rb=0;rb<2;rb++)
    #pragma unroll
    for (int reg=0;reg<16;reg++){
      float cacc = 0.f;
      #pragma unroll
      for (int cb=0;cb<4;cb++)
        cacc = fmaf(fmaxf(Acc[rb][cb][reg] + bvv[cb], 0.f), wvv[cb], cacc);
      #pragma unroll
      for (int off=1; off<32; off<<=1) cacc += __shfl_xor(cacc, off, 64);
      if ((lane & 31) == 0){
        const int row = wm*64 + rb*32 + (reg&3) + 8*(reg>>2) + ((lane>>5)<<2);
        red[wn*128 + row] = cacc;
      }
    }
  __syncthreads();
  if (t < 128){
    float draw = red[t] + red[128 + t];
    (br ? drawH : drawS)[mb*128 + t] = draw;
  }

  if (br == 0){
    const int row = mb*128 + (t >> 1);
    const float* p = imgs + (size_t)row*DD + (t & 1)*256;
    float ss = 0.f;
    #pragma unroll
    for (int q=0;q<64;q++){
      float4 x = ((const float4*)p)[q];
      ss += x.x*x.x + x.y*x.y + x.z*x.z + x.w*x.w;
    }
    ss += __shfl_xor(ss, 1, 64);
    if ((t & 1) == 0) rnraw[row] = ss;
  }
}

// ---------------------------------------------------------------------------
// Epilogue v4 (round-2 verified): single-wave final scalar epilogue.
// ---------------------------------------------------------------------------
__global__ __launch_bounds__(512) void epi_kernel(
    const float* __restrict__ Sp,
    const int* __restrict__ img_lens, const int* __restrict__ cap_lens,
    const float* __restrict__ drawS, const float* __restrict__ drawH,
    const float* __restrict__ rnraw,
    const float* __restrict__ G, const _Float16* __restrict__ Gfrag,
    const float* __restrict__ sb2, const float* __restrict__ hb2,
    float* __restrict__ out)
{
  __shared__ __align__(16) _Float16 sEp[48*72];
  __shared__ __align__(16) _Float16 sE2[48*72];
  __shared__ __align__(16) _Float16 sFp[48*72];
  __shared__ __align__(16) _Float16 sGf[4096];
  __shared__ float sTd[48];
  __shared__ float sTS[48];
  __shared__ float sGd[64];
  __shared__ float sAv[40];
  __shared__ int   sAi[40];

  const int bx = blockIdx.x;
  const int i = bx >> 6, c = bx & 63;
  const int t = threadIdx.x, lane = t & 63;
  const int wv = __builtin_amdgcn_readfirstlane(t >> 6);   // 0..7
  const int cap_len = cap_lens[c];
  const int img_len = img_lens[i];

  ((int4*)sGf)[t] = ((const int4*)(Gfrag + (size_t)c*4096))[t];
  if (t < WW) sGd[t] = G[(size_t)c*WW*WW + t*(WW+1)];

  const int r0 = wv*5;                    // rows r0..r0+4; 36..39 are dummies
  const float* srow = Sp + (size_t)(i*64 + c)*1800u + (size_t)r0*50;
  float sv[5];
  #pragma unroll
  for (int j=0;j<5;j++)
    sv[j] = ((r0+j) < RR && lane < WW) ? srow[j*50 + lane] : 0.f;

  #pragma unroll
  for (int j=0;j<5;j++){
    const int r = r0 + j;
    const float s = sv[j];
    const bool valid = (lane < cap_len);
    float av = wave_max(valid ? s : -INFINITY);
    unsigned long long m = __ballot(valid && (s == av));
    int ai = (int)(__ffsll((long long)m) - 1);
    float e = valid ? __expf(10.0f*(s - av)) : 0.f;
    sEp[r*72 + lane] = (_Float16)e;
    sE2[r*72 + lane] = (_Float16)(e * s);
    if (lane == 0){ sAv[r] = av; sAi[r] = ai; }
  }
  __syncthreads();

  {
    int mi = wv % 3, nt = wv / 3;
    f32x4 acc = (f32x4){0,0,0,0};
    #pragma unroll
    for (int ks=0; ks<2; ks++){
      f16x8 a = *(const f16x8*)&sEp[(mi*16+(lane&15))*72 + ks*32 + ((lane>>4)<<3)];
      f16x8 b = *(const f16x8*)&sGf[(nt*2+ks)*512 + lane*8];
      acc = __builtin_amdgcn_mfma_f32_16x16x32_f16(a, b, acc, 0,0,0);
    }
    #pragma unroll
    for (int reg=0; reg<4; reg++){
      int row = mi*16 + ((lane>>4)<<2) + reg;
      sFp[row*72 + nt*16 + (lane&15)] = (_Float16)acc[reg];
    }
  }
  if (wv < 4){
    int tau = 8 + wv, mi = tau % 3, nt = tau / 3;
    f32x4 acc = (f32x4){0,0,0,0};
    #pragma unroll
    for (int ks=0; ks<2; ks++){
      f16x8 a = *(const f16x8*)&sEp[(mi*16+(lane&15))*72 + ks*32 + ((lane>>4)<<3)];
      f16x8 b = *(const f16x8*)&sGf[(nt*2+ks)*512 + lane*8];
      acc = __builtin_amdgcn_mfma_f32_16x16x32_f16(a, b, acc, 0,0,0);
    }
    #pragma unroll
    for (int reg=0; reg<4; reg++){
      int row = mi*16 + ((lane>>4)<<2) + reg;
      sFp[row*72 + nt*16 + (lane&15)] = (_Float16)acc[reg];
    }
  } else if (wv < 7){
    int mi = wv - 4;
    f32x4 acc = (f32x4){0,0,0,0};
    #pragma unroll
    for (int ks=0; ks<2; ks++){
      f16x8 a = *(const f16x8*)&sE2[(mi*16+(lane&15))*72 + ks*32 + ((lane>>4)<<3)];
      f16x8 b = *(const f16x8*)&sGf[(3*2+ks)*512 + lane*8];
      acc = __builtin_amdgcn_mfma_f32_16x16x32_f16(a, b, acc, 0,0,0);
    }
    if ((lane & 15) == 2){
      #pragma unroll
      for (int reg=0; reg<4; reg++)
        sTS[mi*16 + ((lane>>4)<<2) + reg] = acc[reg];
    }
  }
  __syncthreads();

  if (wv < 3){
    f32x4 acc = (f32x4){0,0,0,0};
    #pragma unroll
    for (int ks=0; ks<2; ks++){
      f16x8 aF = *(const f16x8*)&sFp[(wv*16+(lane&15))*72 + ks*32 + ((lane>>4)<<3)];
      f16x8 bE = *(const f16x8*)&sEp[(wv*16+(lane&15))*72 + ks*32 + ((lane>>4)<<3)];
      acc = __builtin_amdgcn_mfma_f32_16x16x32_f16(aF, bE, acc, 0,0,0);
    }
    #pragma unroll
    for (int reg=0; reg<4; reg++){
      int row = ((lane>>4)<<2) + reg;
      if (row == (lane&15)) sTd[wv*16 + row] = acc[reg];
    }
  }
  __syncthreads();

  // single-wave, one-lane-per-row final epilogue
  if (wv == 0 && lane < RR){
    const int r = lane;
    const int ai = sAi[r];
    const float av = sAv[r];
    float tQ  = sTd[r];
    float tS  = sTS[r];
    float den = (float)sFp[r*72 + 50];
    float dh  = (float)sFp[r*72 + ai];
    float hh  = sGd[ai];
    float hv  = (av > -1.0f) ? 1.f : 0.f;

    const int rg = i*RR + r;
    float sg_ = 1.f/(1.f+__expf(-(drawS[rg] + sb2[0])));
    float hg_ = 1.f/(1.f+__expf(-(drawH[rg] + hb2[0])));
    float tot = sg_ + hg_ + 1e-8f;
    float gs = sg_/tot, gh = hg_/tot;
    float rx = 1.f/fmaxf(sqrtf(rnraw[rg]), 1e-12f);
    float rd = 1.f/den;
    float num = gs*(tS*rd) + hv*gh*av;
    float n2  = gs*gs*(tQ*rd*rd) + hv*(2.f*gs*gh*(dh*rd) + gh*gh*hh);
    float ov  = num * rx / fmaxf(sqrtf(fmaxf(n2, 0.f)), 1e-12f);
    out[((size_t)i*BC + c)*RR + r] = (r < img_len) ? ov : -1.0f;
  }
}

// ---------------------------------------------------------------------------
// Fallback path kernels (round-1 verified), used only if ws too small.
// ---------------------------------------------------------------------------
__global__ __launch_bounds__(256) void gates_kernel(
    const float* __restrict__ imgs,
    const float* __restrict__ sw1, const float* __restrict__ sb1,
    const float* __restrict__ sw2, const float* __restrict__ sb2,
    const float* __restrict__ hw1, const float* __restrict__ hb1,
    const float* __restrict__ hw2, const float* __restrict__ hb2,
    float* __restrict__ sgn, float* __restrict__ hgn, float* __restrict__ rn)
{
  __shared__ __align__(16) float xs[8*DD];
  __shared__ float red[16*256];
  __shared__ float nr[8];
  const int t = threadIdx.x;
  const int row0 = blockIdx.x * 8;
  if (t < 8) nr[t] = 0.f;
  __syncthreads();
  const float4* src = (const float4*)(imgs + (size_t)row0*DD);
  #pragma unroll
  for (int m=0;m<4;m++){
    int n = m*256+t;
    float4 v = src[n];
    ((float4*)xs)[n] = v;
    float ss = v.x*v.x+v.y*v.y+v.z*v.z+v.w*v.w;
    atomicAdd(&nr[n>>7], ss);
  }
  __syncthreads();
  float accS[8]={0,0,0,0,0,0,0,0};
  float accH[8]={0,0,0,0,0,0,0,0};
  for (int k=0;k<DD;k+=4){
    float a0=sw1[(k+0)*HH+t], a1=sw1[(k+1)*HH+t], a2=sw1[(k+2)*HH+t], a3=sw1[(k+3)*HH+t];
    float b0=hw1[(k+0)*HH+t], b1=hw1[(k+1)*HH+t], b2=hw1[(k+2)*HH+t], b3=hw1[(k+3)*HH+t];
    #pragma unroll
    for (int r=0;r<8;r++){
      float4 x = *(const float4*)&xs[r*DD+k];
      accS[r]=fmaf(x.x,a0,accS[r]); accS[r]=fmaf(x.y,a1,accS[r]);
      accS[r]=fmaf(x.z,a2,accS[r]); accS[r]=fmaf(x.w,a3,accS[r]);
      accH[r]=fmaf(x.x,b0,accH[r]); accH[r]=fmaf(x.y,b1,accH[r]);
      accH[r]=fmaf(x.z,b2,accH[r]); accH[r]=fmaf(x.w,b3,accH[r]);
    }
  }
  const float b1s=sb1[t], b1h=hb1[t], w2s=sw2[t], w2h=hw2[t];
  #pragma unroll
  for (int r=0;r<8;r++){
    red[r*256+t]     = w2s * fmaxf(accS[r]+b1s, 0.f);
    red[(8+r)*256+t] = w2h * fmaxf(accH[r]+b1h, 0.f);
  }
  __syncthreads();
  const int wv=t>>6, ln=t&63;
  #pragma unroll
  for (int q=0;q<4;q++){
    int rr_ = wv*4+q;
    float v = red[rr_*256+ln]+red[rr_*256+ln+64]+red[rr_*256+ln+128]+red[rr_*256+ln+192];
    v = wave_sum(v);
    if (ln==0) red[rr_*256] = v;
  }
  __syncthreads();
  if (t<8){
    float os = red[t*256] + sb2[0];
    float oh = red[(8+t)*256] + hb2[0];
    float s = 1.f/(1.f+__expf(-os));
    float h = 1.f/(1.f+__expf(-oh));
    float tot = s+h+1e-8f;
    sgn[row0+t] = s/tot;
    hgn[row0+t] = h/tot;
    rn[row0+t]  = 1.f/fmaxf(sqrtf(nr[t]), 1e-12f);
  }
}

__global__ __launch_bounds__(256) void gram_fb_kernel(
    const float* __restrict__ caps, float* __restrict__ G)
{
  __shared__ __align__(16) float cs[WW*CST];
  const int c    = blockIdx.x >> 2;
  const int tile = blockIdx.x & 3;
  const int w0   = tile*13;
  const int nw   = (tile==3) ? 11 : 13;
  const int t=threadIdx.x, lane=t&63, wv=t>>6;
  const int wl = lane < WW ? lane : WW-1;
  float acc[4]={0.f,0.f,0.f,0.f};
  for (int k0=0;k0<DD;k0+=128){
    __syncthreads();
    for (int n=t;n<WW*32;n+=256){
      int row=n>>5, c4=(n&31)*4;
      *(float4*)&cs[row*CST+c4] = *(const float4*)(caps + ((size_t)c*WW+row)*DD + k0 + c4);
    }
    __syncthreads();
    for (int k=0;k<128;k+=4){
      float4 cv = *(const float4*)&cs[wl*CST+k];
      #pragma unroll
      for (int q=0;q<4;q++){
        int lw = wv + q*4;
        if (lw < nw){
          float4 bv = *(const float4*)&cs[(w0+lw)*CST+k];
          acc[q]=fmaf(bv.x,cv.x,acc[q]); acc[q]=fmaf(bv.y,cv.y,acc[q]);
          acc[q]=fmaf(bv.z,cv.z,acc[q]); acc[q]=fmaf(bv.w,cv.w,acc[q]);
        }
      }
    }
  }
  if (lane < WW){
    #pragma unroll
    for (int q=0;q<4;q++){
      int lw = wv + q*4;
      if (lw < nw) G[(size_t)c*WW*WW + (w0+lw)*WW + lane] = acc[q];
    }
  }
}

__global__ __launch_bounds__(256) void pair_kernel(
    const float* __restrict__ imgs, const float* __restrict__ caps,
    const int* __restrict__ img_lens, const int* __restrict__ cap_lens,
    const float* __restrict__ sgn, const float* __restrict__ hgn,
    const float* __restrict__ rn,
    const float* __restrict__ G, float* __restrict__ out)
{
  __shared__ __align__(16) float smem[WW*CST + 52*52 + RR*52];
  float* cs = smem;
  float* Gs = smem + WW*CST;
  float* As = Gs + 52*52;
  const int bx = blockIdx.x;
  const int i = bx >> 6, c = bx & 63;
  const int t = threadIdx.x, lane = t&63;
  const int wv = __builtin_amdgcn_readfirstlane(t>>6);
  const int wl = lane < WW ? lane : WW-1;
  const int cap_len = cap_lens[c];
  const int img_len = img_lens[i];
  for (int n=t;n<52*52;n+=256){
    int w=n/52, w2=n-w*52;
    Gs[n] = (w<WW && w2<WW) ? G[(size_t)c*WW*WW + w*WW + w2] : 0.f;
  }
  float acc[9]={0,0,0,0,0,0,0,0,0};
  const float* ib = imgs + ((size_t)i*RR + wv*9)*DD;
  for (int k0=0;k0<DD;k0+=128){
    __syncthreads();
    for (int n=t;n<WW*32;n+=256){
      int row=n>>5, c4=(n&31)*4;
      *(float4*)&cs[row*CST+c4] = *(const float4*)(caps + ((size_t)c*WW+row)*DD + k0 + c4);
    }
    __syncthreads();
    for (int k=0;k<128;k+=4){
      float4 cv = *(const float4*)&cs[wl*CST+k];
      #pragma unroll
      for (int j=0;j<9;j++){
        float4 iv = *(const float4*)(ib + j*DD + k0 + k);
        acc[j]=fmaf(iv.x,cv.x,acc[j]); acc[j]=fmaf(iv.y,cv.y,acc[j]);
        acc[j]=fmaf(iv.z,cv.z,acc[j]); acc[j]=fmaf(iv.w,cv.w,acc[j]);
      }
    }
  }
  for (int j=0;j<9;j++){
    const int r = wv*9 + j;
    const float s = acc[j];
    float av; int ai;
    if (lane < cap_len){ av = s;     ai = lane; }
    else if (lane < WW){ av = -1.0f; ai = lane; }
    else               { av = -INFINITY; ai = 64; }
    #pragma unroll
    for (int off=32; off>0; off>>=1){
      float ov = __shfl_xor(av, off, 64);
      int   oi = __shfl_xor(ai, off, 64);
      if (ov > av || (ov == av && oi < ai)){ av = ov; ai = oi; }
    }
    float zv = (lane < cap_len) ? s*10.0f : -INFINITY;
    float zm = wave_max(zv);
    float e  = (lane < cap_len) ? __expf(zv - zm) : 0.f;
    float den = wave_sum(e);
    if (lane < 52) As[r*52 + lane] = (lane < WW) ? e : 0.f;
    float m = 0.f;
    #pragma unroll
    for (int g=0; g<13; g++){
      float4 ab = *(const float4*)&As[r*52 + g*4];
      m = fmaf(ab.x, Gs[(g*4+0)*52+wl], m);
      m = fmaf(ab.y, Gs[(g*4+1)*52+wl], m);
      m = fmaf(ab.z, Gs[(g*4+2)*52+wl], m);
      m = fmaf(ab.w, Gs[(g*4+3)*52+wl], m);
    }
    float tS = wave_sum(e * s);
    float tQ = wave_sum(e * m);
    float dh = __shfl(m, ai, 64);
    float hh = Gs[ai*52 + ai];
    float hv = (ai < cap_len) ? 1.f : 0.f;
    const int rg = i*RR + r;
    float gs = sgn[rg], gh = hgn[rg], rx = rn[rg];
    float rd = 1.f/den;
    float num = gs*(tS*rd) + hv*gh*av;
    float n2  = gs*gs*(tQ*rd*rd) + hv*(2.f*gs*gh*(dh*rd) + gh*gh*hh);
    float ov  = num * rx / fmaxf(sqrtf(fmaxf(n2, 0.f)), 1e-12f);
    if (lane==0) out[((size_t)i*BC + c)*RR + r] = (r < img_len) ? ov : -1.0f;
  }
}

// ---------------------------------------------------------------------------
extern "C" void kernel_launch(void* const* d_in, const int* in_sizes, int n_in,
                              void* d_out, int out_size, void* d_ws, size_t ws_size,
                              hipStream_t stream)
{
  const float* imgs = (const float*)d_in[0];
  const float* caps = (const float*)d_in[1];
  const float* sw1  = (const float*)d_in[2];
  const float* sb1  = (const float*)d_in[3];
  const float* sw2  = (const float*)d_in[4];
  const float* sb2  = (const float*)d_in[5];
  const float* hw1  = (const float*)d_in[6];
  const float* hb1  = (const float*)d_in[7];
  const float* hw2  = (const float*)d_in[8];
  const float* hb2  = (const float*)d_in[9];
  const int* img_lens = (const int*)d_in[10];
  const int* cap_lens = (const int*)d_in[11];

  char* base = (char*)d_ws;
  float*    drawS = (float*)(base + 0);            // raw soft gate sums (2304)
  float*    drawH = (float*)(base + 9216);         // raw hard gate sums (2304)
  float*    rnraw = (float*)(base + 18432);        // raw imgs row sumsq (2304)
  float*    G     = (float*)(base + 27648);        // 640,000  -> 667,648
  _Float16* Gfrag = (_Float16*)(base + 667648);    // 524,288  -> 1,191,936
  _Float16* Ah    = (_Float16*)(base + 1191936);   // 2,359,296 -> 3,551,232
  _Float16* Al    = (_Float16*)(base + 3551232);   // 2,359,296 -> 5,910,528
  _Float16* Bh    = (_Float16*)(base + 5910528);   // 3,801,088 -> 9,711,616
  _Float16* Bl    = (_Float16*)(base + 9711616);   // 3,801,088 -> 13,512,704
  float*    Sp    = (float*)(base + 18231296);     // 29,491,200 -> 47,722,496
  const size_t NEED = 47722496ull;

  float* out = (float*)d_out;

  if (ws_size >= NEED){
    hipLaunchKernelGGL(prepgram_kernel, dim3(1760), dim3(256), 0, stream,
                       imgs, caps, sw1, hw1, Ah, Al, Bh, Bl, G, Gfrag);
    hipLaunchKernelGGL(sgemm_hgate_kernel, dim3(486), dim3(256), 0, stream,
                       Ah, Al, Bh, Bl, Sp,
                       imgs, sb1, hb1, sw2, hw2, drawS, drawH, rnraw);
    hipLaunchKernelGGL(epi_kernel, dim3(BI*BC), dim3(512), 0, stream,
                       Sp, img_lens, cap_lens, drawS, drawH, rnraw,
                       G, Gfrag, sb2, hb2, out);
  } else {
    hipLaunchKernelGGL(gates_kernel, dim3(288), dim3(256), 0, stream,
                       imgs, sw1, sb1, sw2, sb2, hw1, hb1, hw2, hb2,
                       drawS, drawH, rnraw);
    hipLaunchKernelGGL(gram_fb_kernel, dim3(256), dim3(256), 0, stream, caps, G);
    hipLaunchKernelGGL(pair_kernel, dim3(BI*BC), dim3(256), 0, stream,
                       imgs, caps, img_lens, cap_lens, drawS, drawH, rnraw, G, out);
  }
}

// Round 5
// 154.779 us; speedup vs baseline: 1.1516x; 1.1516x over previous
//
#include <hip/hip_runtime.h>
#include <math.h>

#define BI 64
#define RR 36
#define BC 64
#define WW 50
#define DD 512
#define HH 256
#define CST 132

typedef _Float16 f16x8 __attribute__((ext_vector_type(8)));
typedef _Float16 f16x4 __attribute__((ext_vector_type(4)));
typedef float    f32x4 __attribute__((ext_vector_type(4)));
typedef float    f32x16 __attribute__((ext_vector_type(16)));

__device__ __forceinline__ float wave_sum(float v){
  #pragma unroll
  for (int off=32; off>0; off>>=1) v += __shfl_xor(v, off, 64);
  return v;
}
__device__ __forceinline__ float wave_max(float v){
  #pragma unroll
  for (int off=32; off>0; off>>=1) v = fmaxf(v, __shfl_xor(v, off, 64));
  return v;
}

// async global->LDS DMA, 16B per lane (round-3 verified).
__device__ __forceinline__ void gl_lds16(const _Float16* g, _Float16* l){
  __builtin_amdgcn_global_load_lds(
      (const __attribute__((address_space(1))) unsigned int*)g,
      (__attribute__((address_space(3))) unsigned int*)l, 16, 0, 0);
}

// ---------------------------------------------------------------------------
// PrepGram v3 (round-5): prep branch = round-3 verified (16-row tiles for
// 16x16x32 MFMA). Gram branch REPLACED: was 256 VALU blocks w/ redundant LDS
// staging (~13us tail); now 64 MFMA blocks (one per caption), 32x32x16 frags
// (layout HW-verified by round-4 pass), operands read directly from global
// f32 (L2-hot) and hi/lo-split in registers. Zero-padded rows 50..63 give
// exact zeros (same semantics as old Gt zero-init).
// ---------------------------------------------------------------------------
__global__ __launch_bounds__(256) void prepgram_kernel(
    const float* __restrict__ imgs, const float* __restrict__ caps,
    const float* __restrict__ sw1, const float* __restrict__ hw1,
    _Float16* __restrict__ Ah, _Float16* __restrict__ Al,
    _Float16* __restrict__ Bh, _Float16* __restrict__ Bl,
    float* __restrict__ G, _Float16* __restrict__ Gfrag)
{
  __shared__ __align__(16) float smem[64*64];   // gram branch: Gt 64x64 f32
  if (blockIdx.x < 1504){
    int u = blockIdx.x*256 + threadIdx.x;
    _Float16 *dh, *dl; int idx;
    if (u < 144*1024){ idx = u;            dh = Ah; dl = Al; }
    else             { idx = u - 144*1024; dh = Bh; dl = Bl; }
    const int tile = idx >> 10, rem = idx & 1023, ks = rem >> 6, lane = rem & 63;
    const int k0 = ks*32 + (lane >> 4)*8;
    f16x8 hv, lv;
    if (u < 144*1024 || tile < 200){
      const float* src = (u < 144*1024) ? imgs : caps;
      const int m = tile*16 + (lane & 15);
      const float* p = src + (size_t)m*DD + k0;
      #pragma unroll
      for (int j=0;j<8;j++){
        float a = p[j];
        _Float16 h = (_Float16)a;
        hv[j] = h;
        lv[j] = (_Float16)((a - (float)h) * 2048.0f);
      }
    } else {
      const int n = (tile-200)*16 + (lane & 15);          // 0..511
      const float* src = (n < HH) ? (sw1 + n) : (hw1 + n - HH);
      #pragma unroll
      for (int j=0;j<8;j++){
        float a = src[(size_t)(k0+j)*HH];
        _Float16 h = (_Float16)a;
        hv[j] = h;
        lv[j] = (_Float16)((a - (float)h) * 2048.0f);
      }
    }
    *(f16x8*)(dh + (size_t)idx*8) = hv;
    *(f16x8*)(dl + (size_t)idx*8) = lv;
  } else {
    // ---------------- gram body v2: MFMA per caption ----------------
    float* Gt = smem;                       // 64x64 f32
    const int c = blockIdx.x - 1504;        // 0..63
    const int t = threadIdx.x, lane = t & 63, wv = t >> 6;   // 4 waves
    const int wm = wv & 1, wn = wv >> 1;    // 32-row / 32-col tile select
    const float* cbase = caps + (size_t)c*WW*DD;

    f32x16 P, Q;
    #pragma unroll
    for (int e=0;e<16;e++){ P[e]=0.f; Q[e]=0.f; }

    const int r  = lane & 31;
    const int k8 = (lane >> 5)*8;
    const int wA = wm*32 + r;               // A row (word), pad >=50
    const int wB = wn*32 + r;               // B col (word), pad >=50
    const float* pA = cbase + (size_t)wA*DD + k8;
    const float* pB = cbase + (size_t)wB*DD + k8;

    for (int ks=0; ks<32; ks++){
      const int k0 = ks*16;
      float4 a0, a1, b0, b1;
      if (wA < WW){ a0 = *(const float4*)(pA + k0); a1 = *(const float4*)(pA + k0 + 4); }
      else        { a0 = (float4){0,0,0,0}; a1 = a0; }
      if (wB < WW){ b0 = *(const float4*)(pB + k0); b1 = *(const float4*)(pB + k0 + 4); }
      else        { b0 = (float4){0,0,0,0}; b1 = b0; }
      float av[8] = {a0.x,a0.y,a0.z,a0.w,a1.x,a1.y,a1.z,a1.w};
      float bw[8] = {b0.x,b0.y,b0.z,b0.w,b1.x,b1.y,b1.z,b1.w};
      f16x8 ah, al, bh, bl;
      #pragma unroll
      for (int j=0;j<8;j++){
        _Float16 h = (_Float16)av[j];
        ah[j] = h; al[j] = (_Float16)((av[j]-(float)h)*2048.0f);
        _Float16 g = (_Float16)bw[j];
        bh[j] = g; bl[j] = (_Float16)((bw[j]-(float)g)*2048.0f);
      }
      P = __builtin_amdgcn_mfma_f32_32x32x16_f16(ah, bh, P,0,0,0);
      Q = __builtin_amdgcn_mfma_f32_32x32x16_f16(ah, bl, Q,0,0,0);
      Q = __builtin_amdgcn_mfma_f32_32x32x16_f16(al, bh, Q,0,0,0);
    }

    // C layout (HW-verified r4): col=lane&31, row=(reg&3)+8*(reg>>2)+4*(lane>>5)
    const int col = wn*32 + (lane & 31);
    #pragma unroll
    for (int reg=0; reg<16; reg++){
      const int row = wm*32 + (reg&3) + 8*(reg>>2) + 4*(lane>>5);
      float g = P[reg] + Q[reg]*(1.0f/2048.0f);
      Gt[row*64 + col] = g;
      if (row < WW && col < WW)
        G[(size_t)c*WW*WW + row*WW + col] = g;
    }
    __syncthreads();

    // Gfrag build: index-identical to round-3 (per 16-col tile), looped x4.
    #pragma unroll
    for (int tile=0; tile<4; tile++){
      int flat = t*4;
      int ks2 = flat>>9, L=(flat>>3)&63, j0=flat&7;
      const bool ones = (tile==3) && ((L&15)==2);   // frag n == 50
      int n  = tile*16 + (L&15);
      int kk = ks2*32 + ((L>>4)<<3) + j0;
      f16x4 v;
      #pragma unroll
      for (int e=0;e<4;e++)
        v[e] = ones ? (_Float16)1.0f : (_Float16)Gt[n*64 + kk + e];
      *(f16x4*)&Gfrag[(size_t)c*4096 + (tile*2+ks2)*512 + L*8 + j0] = v;
    }
  }
}

// ---------------------------------------------------------------------------
// Combined S-GEMM + gate-GEMM (round-3 verified form, reverted from round-4).
//  Staging via global_load_lds DMA; one barrier per K-step; 2x16KB buffers.
// ---------------------------------------------------------------------------
__global__ __launch_bounds__(256, 2) void sgemm_hgate_kernel(
    const _Float16* __restrict__ Ah, const _Float16* __restrict__ Al,
    const _Float16* __restrict__ Bh, const _Float16* __restrict__ Bl,
    float* __restrict__ Sp,
    const float* __restrict__ imgs,
    const float* __restrict__ sb1, const float* __restrict__ hb1,
    const float* __restrict__ sw2, const float* __restrict__ hw2,
    float* __restrict__ drawS, float* __restrict__ drawH,
    float* __restrict__ rnraw)
{
  __shared__ _Float16 lds[2*16384];
  const int t = threadIdx.x, lane = t & 63, wv = t >> 6;

  if (blockIdx.x >= 36){
    // ---------------- sgemm body ----------------
    const int bx = blockIdx.x - 36;
    const int mb = bx % 18, nb = bx / 18;
    const int wm = wv & 1, wn = wv >> 1;

    f32x4 P[4][4], Q[4][4];
    #pragma unroll
    for (int a=0;a<4;a++)
      #pragma unroll
      for (int b=0;b<4;b++){ P[a][b]=(f32x4){0,0,0,0}; Q[a][b]=(f32x4){0,0,0,0}; }

    const _Float16* sbase = (wv==0)?Ah:(wv==1)?Al:(wv==2)?Bh:Bl;
    const size_t gtb = (size_t)((wv<2)? mb : nb)*8;
    _Float16* buf0 = lds + wv*4096;
    _Float16* buf1 = lds + 16384 + wv*4096;

    // prologue: DMA-stage ks=0 into buf0
    #pragma unroll
    for (int s=0;s<8;s++)
      gl_lds16(sbase + (((gtb+s)*16 + 0)*64 + lane)*8, buf0 + s*512);
    asm volatile("s_waitcnt vmcnt(0)" ::: "memory");
    __syncthreads();

    for (int ks=0; ks<16; ks++){
      if (ks < 15){
        _Float16* nb_ = ((ks+1) & 1) ? buf1 : buf0;
        #pragma unroll
        for (int s=0;s<8;s++)
          gl_lds16(sbase + (((gtb+s)*16 + (ks+1))*64 + lane)*8, nb_ + s*512);
      }

      const _Float16* L = lds + (ks & 1)*16384;
      f16x8 a_h[4], a_l[4], b_h[4], b_l[4];
      #pragma unroll
      for (int x=0;x<4;x++){
        a_h[x] = *(const f16x8*)&L[        (wm*4+x)*512 + lane*8];
        a_l[x] = *(const f16x8*)&L[ 4096 + (wm*4+x)*512 + lane*8];
        b_h[x] = *(const f16x8*)&L[ 8192 + (wn*4+x)*512 + lane*8];
        b_l[x] = *(const f16x8*)&L[12288 + (wn*4+x)*512 + lane*8];
      }
      #pragma unroll
      for (int mi=0;mi<4;mi++)
        #pragma unroll
        for (int ni=0;ni<4;ni++){
          P[mi][ni] = __builtin_amdgcn_mfma_f32_16x16x32_f16(a_h[mi], b_h[ni], P[mi][ni],0,0,0);
          Q[mi][ni] = __builtin_amdgcn_mfma_f32_16x16x32_f16(a_h[mi], b_l[ni], Q[mi][ni],0,0,0);
          Q[mi][ni] = __builtin_amdgcn_mfma_f32_16x16x32_f16(a_l[mi], b_h[ni], Q[mi][ni],0,0,0);
        }

      if (ks < 15)
        asm volatile("s_waitcnt vmcnt(0)" ::: "memory");  // next buf landed
      __syncthreads();
    }

    const int r0 = mb*128 + wm*64 + ((lane>>4)<<2);
    const int c0 = nb*128 + wn*64 + (lane&15);
    size_t pr[16]; size_t pc[4];
    #pragma unroll
    for (int mi=0;mi<4;mi++)
      #pragma unroll
      for (int reg=0;reg<4;reg++){
        unsigned row = (unsigned)(r0 + mi*16 + reg);
        unsigned i = row / 36u, rr_ = row - i*36u;
        pr[mi*4+reg] = (size_t)i*115200u + (size_t)rr_*50u;
      }
    #pragma unroll
    for (int ni=0;ni<4;ni++){
      unsigned col = (unsigned)(c0 + ni*16);
      unsigned cc = col / 50u, w = col - cc*50u;
      pc[ni] = (size_t)cc*1800u + w;
    }
    #pragma unroll
    for (int mi=0;mi<4;mi++)
      #pragma unroll
      for (int ni=0;ni<4;ni++)
        #pragma unroll
        for (int reg=0;reg<4;reg++)
          Sp[pr[mi*4+reg] + pc[ni]] =
              P[mi][ni][reg] + Q[mi][ni][reg]*(1.0f/2048.0f);
    return;
  }

  // ---------------- hgate body ----------------
  const int mb = blockIdx.x >> 1;
  const int br = blockIdx.x & 1;          // 0 = soft, 1 = hard
  const int wm = wv & 1, wn = wv >> 1;

  f32x4 P[4][8];
  #pragma unroll
  for (int a=0;a<4;a++)
    #pragma unroll
    for (int b=0;b<8;b++) P[a][b]=(f32x4){0,0,0,0};

  const _Float16* Bbase = Bh + (size_t)(200 + br*16)*8192;

  // prologue DMA-stage ks=0
  #pragma unroll
  for (int s=0;s<6;s++){
    const int u = wv*6 + s;
    const _Float16* src = (u < 8)
      ? (Ah    + ((size_t)((mb*8 + u)*16 + 0)*64 + lane)*8)
      : (Bbase + ((size_t)((u-8)  *16 + 0)*64 + lane)*8);
    _Float16* dst = (u < 8) ? (lds + u*512) : (lds + 4096 + (u-8)*512);
    gl_lds16(src, dst);
  }
  asm volatile("s_waitcnt vmcnt(0)" ::: "memory");
  __syncthreads();

  for (int ks=0; ks<16; ks++){
    if (ks < 15){
      _Float16* buf = lds + (((ks+1) & 1) ? 16384 : 0);
      #pragma unroll
      for (int s=0;s<6;s++){
        const int u = wv*6 + s;
        const _Float16* src = (u < 8)
          ? (Ah    + ((size_t)((mb*8 + u)*16 + (ks+1))*64 + lane)*8)
          : (Bbase + ((size_t)((u-8)  *16 + (ks+1))*64 + lane)*8);
        _Float16* dst = (u < 8) ? (buf + u*512) : (buf + 4096 + (u-8)*512);
        gl_lds16(src, dst);
      }
    }

    const _Float16* L = lds + (ks & 1)*16384;
    f16x8 a[4], b[8];
    #pragma unroll
    for (int x=0;x<4;x++)
      a[x] = *(const f16x8*)&L[(wm*4+x)*512 + lane*8];
    #pragma unroll
    for (int y=0;y<8;y++)
      b[y] = *(const f16x8*)&L[4096 + (wn*8+y)*512 + lane*8];
    #pragma unroll
    for (int mi=0;mi<4;mi++)
      #pragma unroll
      for (int ni=0;ni<8;ni++)
        P[mi][ni] = __builtin_amdgcn_mfma_f32_16x16x32_f16(a[mi], b[ni], P[mi][ni],0,0,0);

    if (ks < 15)
      asm volatile("s_waitcnt vmcnt(0)" ::: "memory");
    __syncthreads();
  }

  const float* b1 = br ? hb1 : sb1;
  const float* w2 = br ? hw2 : sw2;
  float bvv[8], wvv[8];
  #pragma unroll
  for (int ni=0;ni<8;ni++){
    const int cb = wn*128 + ni*16 + (lane&15);
    bvv[ni] = b1[cb]; wvv[ni] = w2[cb];
  }
  float contrib[16];
  #pragma unroll
  for (int mi=0;mi<4;mi++)
    #pragma unroll
    for (int reg=0;reg<4;reg++){
      float cacc = 0.f;
      #pragma unroll
      for (int ni=0;ni<8;ni++)
        cacc = fmaf(fmaxf(P[mi][ni][reg] + bvv[ni], 0.f), wvv[ni], cacc);
      #pragma unroll
      for (int off=1; off<16; off<<=1) cacc += __shfl_xor(cacc, off, 64);
      contrib[mi*4+reg] = cacc;
    }

  float* red = (float*)lds;
  if ((lane & 15) == 0){
    const int rbase = wm*64 + ((lane>>4)<<2);
    #pragma unroll
    for (int mi=0;mi<4;mi++)
      #pragma unroll
      for (int reg=0;reg<4;reg++)
        red[wn*128 + rbase + mi*16 + reg] = contrib[mi*4+reg];
  }
  __syncthreads();
  if (t < 128){
    float draw = red[t] + red[128 + t];
    (br ? drawH : drawS)[mb*128 + t] = draw;
  }

  if (br == 0){
    const int row = mb*128 + (t >> 1);
    const float* p = imgs + (size_t)row*DD + (t & 1)*256;
    float ss = 0.f;
    #pragma unroll
    for (int q=0;q<64;q++){
      float4 x = ((const float4*)p)[q];
      ss += x.x*x.x + x.y*x.y + x.z*x.z + x.w*x.w;
    }
    ss += __shfl_xor(ss, 1, 64);
    if ((t & 1) == 0) rnraw[row] = ss;
  }
}

// ---------------------------------------------------------------------------
// Epilogue v4 (round-2 verified): single-wave final scalar epilogue.
// ---------------------------------------------------------------------------
__global__ __launch_bounds__(512) void epi_kernel(
    const float* __restrict__ Sp,
    const int* __restrict__ img_lens, const int* __restrict__ cap_lens,
    const float* __restrict__ drawS, const float* __restrict__ drawH,
    const float* __restrict__ rnraw,
    const float* __restrict__ G, const _Float16* __restrict__ Gfrag,
    const float* __restrict__ sb2, const float* __restrict__ hb2,
    float* __restrict__ out)
{
  __shared__ __align__(16) _Float16 sEp[48*72];
  __shared__ __align__(16) _Float16 sE2[48*72];
  __shared__ __align__(16) _Float16 sFp[48*72];
  __shared__ __align__(16) _Float16 sGf[4096];
  __shared__ float sTd[48];
  __shared__ float sTS[48];
  __shared__ float sGd[64];
  __shared__ float sAv[40];
  __shared__ int   sAi[40];

  const int bx = blockIdx.x;
  const int i = bx >> 6, c = bx & 63;
  const int t = threadIdx.x, lane = t & 63;
  const int wv = __builtin_amdgcn_readfirstlane(t >> 6);   // 0..7
  const int cap_len = cap_lens[c];
  const int img_len = img_lens[i];

  ((int4*)sGf)[t] = ((const int4*)(Gfrag + (size_t)c*4096))[t];
  if (t < WW) sGd[t] = G[(size_t)c*WW*WW + t*(WW+1)];

  const int r0 = wv*5;                    // rows r0..r0+4; 36..39 are dummies
  const float* srow = Sp + (size_t)(i*64 + c)*1800u + (size_t)r0*50;
  float sv[5];
  #pragma unroll
  for (int j=0;j<5;j++)
    sv[j] = ((r0+j) < RR && lane < WW) ? srow[j*50 + lane] : 0.f;

  #pragma unroll
  for (int j=0;j<5;j++){
    const int r = r0 + j;
    const float s = sv[j];
    const bool valid = (lane < cap_len);
    float av = wave_max(valid ? s : -INFINITY);
    unsigned long long m = __ballot(valid && (s == av));
    int ai = (int)(__ffsll((long long)m) - 1);
    float e = valid ? __expf(10.0f*(s - av)) : 0.f;
    sEp[r*72 + lane] = (_Float16)e;
    sE2[r*72 + lane] = (_Float16)(e * s);
    if (lane == 0){ sAv[r] = av; sAi[r] = ai; }
  }
  __syncthreads();

  {
    int mi = wv % 3, nt = wv / 3;
    f32x4 acc = (f32x4){0,0,0,0};
    #pragma unroll
    for (int ks=0; ks<2; ks++){
      f16x8 a = *(const f16x8*)&sEp[(mi*16+(lane&15))*72 + ks*32 + ((lane>>4)<<3)];
      f16x8 b = *(const f16x8*)&sGf[(nt*2+ks)*512 + lane*8];
      acc = __builtin_amdgcn_mfma_f32_16x16x32_f16(a, b, acc, 0,0,0);
    }
    #pragma unroll
    for (int reg=0; reg<4; reg++){
      int row = mi*16 + ((lane>>4)<<2) + reg;
      sFp[row*72 + nt*16 + (lane&15)] = (_Float16)acc[reg];
    }
  }
  if (wv < 4){
    int tau = 8 + wv, mi = tau % 3, nt = tau / 3;
    f32x4 acc = (f32x4){0,0,0,0};
    #pragma unroll
    for (int ks=0; ks<2; ks++){
      f16x8 a = *(const f16x8*)&sEp[(mi*16+(lane&15))*72 + ks*32 + ((lane>>4)<<3)];
      f16x8 b = *(const f16x8*)&sGf[(nt*2+ks)*512 + lane*8];
      acc = __builtin_amdgcn_mfma_f32_16x16x32_f16(a, b, acc, 0,0,0);
    }
    #pragma unroll
    for (int reg=0; reg<4; reg++){
      int row = mi*16 + ((lane>>4)<<2) + reg;
      sFp[row*72 + nt*16 + (lane&15)] = (_Float16)acc[reg];
    }
  } else if (wv < 7){
    int mi = wv - 4;
    f32x4 acc = (f32x4){0,0,0,0};
    #pragma unroll
    for (int ks=0; ks<2; ks++){
      f16x8 a = *(const f16x8*)&sE2[(mi*16+(lane&15))*72 + ks*32 + ((lane>>4)<<3)];
      f16x8 b = *(const f16x8*)&sGf[(3*2+ks)*512 + lane*8];
      acc = __builtin_amdgcn_mfma_f32_16x16x32_f16(a, b, acc, 0,0,0);
    }
    if ((lane & 15) == 2){
      #pragma unroll
      for (int reg=0; reg<4; reg++)
        sTS[mi*16 + ((lane>>4)<<2) + reg] = acc[reg];
    }
  }
  __syncthreads();

  if (wv < 3){
    f32x4 acc = (f32x4){0,0,0,0};
    #pragma unroll
    for (int ks=0; ks<2; ks++){
      f16x8 aF = *(const f16x8*)&sFp[(wv*16+(lane&15))*72 + ks*32 + ((lane>>4)<<3)];
      f16x8 bE = *(const f16x8*)&sEp[(wv*16+(lane&15))*72 + ks*32 + ((lane>>4)<<3)];
      acc = __builtin_amdgcn_mfma_f32_16x16x32_f16(aF, bE, acc, 0,0,0);
    }
    #pragma unroll
    for (int reg=0; reg<4; reg++){
      int row = ((lane>>4)<<2) + reg;
      if (row == (lane&15)) sTd[wv*16 + row] = acc[reg];
    }
  }
  __syncthreads();

  // single-wave, one-lane-per-row final epilogue
  if (wv == 0 && lane < RR){
    const int r = lane;
    const int ai = sAi[r];
    const float av = sAv[r];
    float tQ  = sTd[r];
    float tS  = sTS[r];
    float den = (float)sFp[r*72 + 50];
    float dh  = (float)sFp[r*72 + ai];
    float hh  = sGd[ai];
    float hv  = (av > -1.0f) ? 1.f : 0.f;

    const int rg = i*RR + r;
    float sg_ = 1.f/(1.f+__expf(-(drawS[rg] + sb2[0])));
    float hg_ = 1.f/(1.f+__expf(-(drawH[rg] + hb2[0])));
    float tot = sg_ + hg_ + 1e-8f;
    float gs = sg_/tot, gh = hg_/tot;
    float rx = 1.f/fmaxf(sqrtf(rnraw[rg]), 1e-12f);
    float rd = 1.f/den;
    float num = gs*(tS*rd) + hv*gh*av;
    float n2  = gs*gs*(tQ*rd*rd) + hv*(2.f*gs*gh*(dh*rd) + gh*gh*hh);
    float ov  = num * rx / fmaxf(sqrtf(fmaxf(n2, 0.f)), 1e-12f);
    out[((size_t)i*BC + c)*RR + r] = (r < img_len) ? ov : -1.0f;
  }
}

// ---------------------------------------------------------------------------
// Fallback path kernels (round-1 verified), used only if ws too small.
// ---------------------------------------------------------------------------
__global__ __launch_bounds__(256) void gates_kernel(
    const float* __restrict__ imgs,
    const float* __restrict__ sw1, const float* __restrict__ sb1,
    const float* __restrict__ sw2, const float* __restrict__ sb2,
    const float* __restrict__ hw1, const float* __restrict__ hb1,
    const float* __restrict__ hw2, const float* __restrict__ hb2,
    float* __restrict__ sgn, float* __restrict__ hgn, float* __restrict__ rn)
{
  __shared__ __align__(16) float xs[8*DD];
  __shared__ float red[16*256];
  __shared__ float nr[8];
  const int t = threadIdx.x;
  const int row0 = blockIdx.x * 8;
  if (t < 8) nr[t] = 0.f;
  __syncthreads();
  const float4* src = (const float4*)(imgs + (size_t)row0*DD);
  #pragma unroll
  for (int m=0;m<4;m++){
    int n = m*256+t;
    float4 v = src[n];
    ((float4*)xs)[n] = v;
    float ss = v.x*v.x+v.y*v.y+v.z*v.z+v.w*v.w;
    atomicAdd(&nr[n>>7], ss);
  }
  __syncthreads();
  float accS[8]={0,0,0,0,0,0,0,0};
  float accH[8]={0,0,0,0,0,0,0,0};
  for (int k=0;k<DD;k+=4){
    float a0=sw1[(k+0)*HH+t], a1=sw1[(k+1)*HH+t], a2=sw1[(k+2)*HH+t], a3=sw1[(k+3)*HH+t];
    float b0=hw1[(k+0)*HH+t], b1=hw1[(k+1)*HH+t], b2=hw1[(k+2)*HH+t], b3=hw1[(k+3)*HH+t];
    #pragma unroll
    for (int r=0;r<8;r++){
      float4 x = *(const float4*)&xs[r*DD+k];
      accS[r]=fmaf(x.x,a0,accS[r]); accS[r]=fmaf(x.y,a1,accS[r]);
      accS[r]=fmaf(x.z,a2,accS[r]); accS[r]=fmaf(x.w,a3,accS[r]);
      accH[r]=fmaf(x.x,b0,accH[r]); accH[r]=fmaf(x.y,b1,accH[r]);
      accH[r]=fmaf(x.z,b2,accH[r]); accH[r]=fmaf(x.w,b3,accH[r]);
    }
  }
  const float b1s=sb1[t], b1h=hb1[t], w2s=sw2[t], w2h=hw2[t];
  #pragma unroll
  for (int r=0;r<8;r++){
    red[r*256+t]     = w2s * fmaxf(accS[r]+b1s, 0.f);
    red[(8+r)*256+t] = w2h * fmaxf(accH[r]+b1h, 0.f);
  }
  __syncthreads();
  const int wv=t>>6, ln=t&63;
  #pragma unroll
  for (int q=0;q<4;q++){
    int rr_ = wv*4+q;
    float v = red[rr_*256+ln]+red[rr_*256+ln+64]+red[rr_*256+ln+128]+red[rr_*256+ln+192];
    v = wave_sum(v);
    if (ln==0) red[rr_*256] = v;
  }
  __syncthreads();
  if (t<8){
    float os = red[t*256] + sb2[0];
    float oh = red[(8+t)*256] + hb2[0];
    float s = 1.f/(1.f+__expf(-os));
    float h = 1.f/(1.f+__expf(-oh));
    float tot = s+h+1e-8f;
    sgn[row0+t] = s/tot;
    hgn[row0+t] = h/tot;
    rn[row0+t]  = 1.f/fmaxf(sqrtf(nr[t]), 1e-12f);
  }
}

__global__ __launch_bounds__(256) void gram_fb_kernel(
    const float* __restrict__ caps, float* __restrict__ G)
{
  __shared__ __align__(16) float cs[WW*CST];
  const int c    = blockIdx.x >> 2;
  const int tile = blockIdx.x & 3;
  const int w0   = tile*13;
  const int nw   = (tile==3) ? 11 : 13;
  const int t=threadIdx.x, lane=t&63, wv=t>>6;
  const int wl = lane < WW ? lane : WW-1;
  float acc[4]={0.f,0.f,0.f,0.f};
  for (int k0=0;k0<DD;k0+=128){
    __syncthreads();
    for (int n=t;n<WW*32;n+=256){
      int row=n>>5, c4=(n&31)*4;
      *(float4*)&cs[row*CST+c4] = *(const float4*)(caps + ((size_t)c*WW+row)*DD + k0 + c4);
    }
    __syncthreads();
    for (int k=0;k<128;k+=4){
      float4 cv = *(const float4*)&cs[wl*CST+k];
      #pragma unroll
      for (int q=0;q<4;q++){
        int lw = wv + q*4;
        if (lw < nw){
          float4 bv = *(const float4*)&cs[(w0+lw)*CST+k];
          acc[q]=fmaf(bv.x,cv.x,acc[q]); acc[q]=fmaf(bv.y,cv.y,acc[q]);
          acc[q]=fmaf(bv.z,cv.z,acc[q]); acc[q]=fmaf(bv.w,cv.w,acc[q]);
        }
      }
    }
  }
  if (lane < WW){
    #pragma unroll
    for (int q=0;q<4;q++){
      int lw = wv + q*4;
      if (lw < nw) G[(size_t)c*WW*WW + (w0+lw)*WW + lane] = acc[q];
    }
  }
}

__global__ __launch_bounds__(256) void pair_kernel(
    const float* __restrict__ imgs, const float* __restrict__ caps,
    const int* __restrict__ img_lens, const int* __restrict__ cap_lens,
    const float* __restrict__ sgn, const float* __restrict__ hgn,
    const float* __restrict__ rn,
    const float* __restrict__ G, float* __restrict__ out)
{
  __shared__ __align__(16) float smem[WW*CST + 52*52 + RR*52];
  float* cs = smem;
  float* Gs = smem + WW*CST;
  float* As = Gs + 52*52;
  const int bx = blockIdx.x;
  const int i = bx >> 6, c = bx & 63;
  const int t = threadIdx.x, lane = t&63;
  const int wv = __builtin_amdgcn_readfirstlane(t>>6);
  const int wl = lane < WW ? lane : WW-1;
  const int cap_len = cap_lens[c];
  const int img_len = img_lens[i];
  for (int n=t;n<52*52;n+=256){
    int w=n/52, w2=n-w*52;
    Gs[n] = (w<WW && w2<WW) ? G[(size_t)c*WW*WW + w*WW + w2] : 0.f;
  }
  float acc[9]={0,0,0,0,0,0,0,0,0};
  const float* ib = imgs + ((size_t)i*RR + wv*9)*DD;
  for (int k0=0;k0<DD;k0+=128){
    __syncthreads();
    for (int n=t;n<WW*32;n+=256){
      int row=n>>5, c4=(n&31)*4;
      *(float4*)&cs[row*CST+c4] = *(const float4*)(caps + ((size_t)c*WW+row)*DD + k0 + c4);
    }
    __syncthreads();
    for (int k=0;k<128;k+=4){
      float4 cv = *(const float4*)&cs[wl*CST+k];
      #pragma unroll
      for (int j=0;j<9;j++){
        float4 iv = *(const float4*)(ib + j*DD + k0 + k);
        acc[j]=fmaf(iv.x,cv.x,acc[j]); acc[j]=fmaf(iv.y,cv.y,acc[j]);
        acc[j]=fmaf(iv.z,cv.z,acc[j]); acc[j]=fmaf(iv.w,cv.w,acc[j]);
      }
    }
  }
  for (int j=0;j<9;j++){
    const int r = wv*9 + j;
    const float s = acc[j];
    float av; int ai;
    if (lane < cap_len){ av = s;     ai = lane; }
    else if (lane < WW){ av = -1.0f; ai = lane; }
    else               { av = -INFINITY; ai = 64; }
    #pragma unroll
    for (int off=32; off>0; off>>=1){
      float ov = __shfl_xor(av, off, 64);
      int   oi = __shfl_xor(ai, off, 64);
      if (ov > av || (ov == av && oi < ai)){ av = ov; ai = oi; }
    }
    float zv = (lane < cap_len) ? s*10.0f : -INFINITY;
    float zm = wave_max(zv);
    float e  = (lane < cap_len) ? __expf(zv - zm) : 0.f;
    float den = wave_sum(e);
    if (lane < 52) As[r*52 + lane] = (lane < WW) ? e : 0.f;
    float m = 0.f;
    #pragma unroll
    for (int g=0; g<13; g++){
      float4 ab = *(const float4*)&As[r*52 + g*4];
      m = fmaf(ab.x, Gs[(g*4+0)*52+wl], m);
      m = fmaf(ab.y, Gs[(g*4+1)*52+wl], m);
      m = fmaf(ab.z, Gs[(g*4+2)*52+wl], m);
      m = fmaf(ab.w, Gs[(g*4+3)*52+wl], m);
    }
    float tS = wave_sum(e * s);
    float tQ = wave_sum(e * m);
    float dh = __shfl(m, ai, 64);
    float hh = Gs[ai*52 + ai];
    float hv = (ai < cap_len) ? 1.f : 0.f;
    const int rg = i*RR + r;
    float gs = sgn[rg], gh = hgn[rg], rx = rn[rg];
    float rd = 1.f/den;
    float num = gs*(tS*rd) + hv*gh*av;
    float n2  = gs*gs*(tQ*rd*rd) + hv*(2.f*gs*gh*(dh*rd) + gh*gh*hh);
    float ov  = num * rx / fmaxf(sqrtf(fmaxf(n2, 0.f)), 1e-12f);
    if (lane==0) out[((size_t)i*BC + c)*RR + r] = (r < img_len) ? ov : -1.0f;
  }
}

// ---------------------------------------------------------------------------
extern "C" void kernel_launch(void* const* d_in, const int* in_sizes, int n_in,
                              void* d_out, int out_size, void* d_ws, size_t ws_size,
                              hipStream_t stream)
{
  const float* imgs = (const float*)d_in[0];
  const float* caps = (const float*)d_in[1];
  const float* sw1  = (const float*)d_in[2];
  const float* sb1  = (const float*)d_in[3];
  const float* sw2  = (const float*)d_in[4];
  const float* sb2  = (const float*)d_in[5];
  const float* hw1  = (const float*)d_in[6];
  const float* hb1  = (const float*)d_in[7];
  const float* hw2  = (const float*)d_in[8];
  const float* hb2  = (const float*)d_in[9];
  const int* img_lens = (const int*)d_in[10];
  const int* cap_lens = (const int*)d_in[11];

  char* base = (char*)d_ws;
  float*    drawS = (float*)(base + 0);            // raw soft gate sums (2304)
  float*    drawH = (float*)(base + 9216);         // raw hard gate sums (2304)
  float*    rnraw = (float*)(base + 18432);        // raw imgs row sumsq (2304)
  float*    G     = (float*)(base + 27648);        // 640,000  -> 667,648
  _Float16* Gfrag = (_Float16*)(base + 667648);    // 524,288  -> 1,191,936
  _Float16* Ah    = (_Float16*)(base + 1191936);   // 2,359,296 -> 3,551,232
  _Float16* Al    = (_Float16*)(base + 3551232);   // 2,359,296 -> 5,910,528
  _Float16* Bh    = (_Float16*)(base + 5910528);   // 3,801,088 -> 9,711,616
  _Float16* Bl    = (_Float16*)(base + 9711616);   // 3,801,088 -> 13,512,704
  float*    Sp    = (float*)(base + 18231296);     // 29,491,200 -> 47,722,496
  const size_t NEED = 47722496ull;

  float* out = (float*)d_out;

  if (ws_size >= NEED){
    hipLaunchKernelGGL(prepgram_kernel, dim3(1568), dim3(256), 0, stream,
                       imgs, caps, sw1, hw1, Ah, Al, Bh, Bl, G, Gfrag);
    hipLaunchKernelGGL(sgemm_hgate_kernel, dim3(486), dim3(256), 0, stream,
                       Ah, Al, Bh, Bl, Sp,
                       imgs, sb1, hb1, sw2, hw2, drawS, drawH, rnraw);
    hipLaunchKernelGGL(epi_kernel, dim3(BI*BC), dim3(512), 0, stream,
                       Sp, img_lens, cap_lens, drawS, drawH, rnraw,
                       G, Gfrag, sb2, hb2, out);
  } else {
    hipLaunchKernelGGL(gates_kernel, dim3(288), dim3(256), 0, stream,
                       imgs, sw1, sb1, sw2, sb2, hw1, hb1, hw2, hb2,
                       drawS, drawH, rnraw);
    hipLaunchKernelGGL(gram_fb_kernel, dim3(256), dim3(256), 0, stream, caps, G);
    hipLaunchKernelGGL(pair_kernel, dim3(BI*BC), dim3(256), 0, stream,
                       imgs, caps, img_lens, cap_lens, drawS, drawH, rnraw, G, out);
  }
}

// Round 6
// 152.554 us; speedup vs baseline: 1.1684x; 1.0146x over previous
//
#include <hip/hip_runtime.h>
#include <math.h>

#define BI 64
#define RR 36
#define BC 64
#define WW 50
#define DD 512
#define HH 256
#define CST 132

typedef _Float16 f16x8 __attribute__((ext_vector_type(8)));
typedef _Float16 f16x4 __attribute__((ext_vector_type(4)));
typedef float    f32x4 __attribute__((ext_vector_type(4)));
typedef float    f32x16 __attribute__((ext_vector_type(16)));

__device__ __forceinline__ float wave_sum(float v){
  #pragma unroll
  for (int off=32; off>0; off>>=1) v += __shfl_xor(v, off, 64);
  return v;
}
__device__ __forceinline__ float wave_max(float v){
  #pragma unroll
  for (int off=32; off>0; off>>=1) v = fmaxf(v, __shfl_xor(v, off, 64));
  return v;
}

// async global->LDS DMA, 16B per lane (round-3 verified).
__device__ __forceinline__ void gl_lds16(const _Float16* g, _Float16* l){
  __builtin_amdgcn_global_load_lds(
      (const __attribute__((address_space(1))) unsigned int*)g,
      (__attribute__((address_space(3))) unsigned int*)l, 16, 0, 0);
}

// ---------------------------------------------------------------------------
// PrepGram v3 (round-5 verified): prep branch 16-row tiles; gram branch =
// 64 MFMA blocks (32x32x16, layout HW-verified r4), operands from global f32.
// ---------------------------------------------------------------------------
__global__ __launch_bounds__(256) void prepgram_kernel(
    const float* __restrict__ imgs, const float* __restrict__ caps,
    const float* __restrict__ sw1, const float* __restrict__ hw1,
    _Float16* __restrict__ Ah, _Float16* __restrict__ Al,
    _Float16* __restrict__ Bh, _Float16* __restrict__ Bl,
    float* __restrict__ G, _Float16* __restrict__ Gfrag)
{
  __shared__ __align__(16) float smem[64*64];   // gram branch: Gt 64x64 f32
  if (blockIdx.x < 1504){
    int u = blockIdx.x*256 + threadIdx.x;
    _Float16 *dh, *dl; int idx;
    if (u < 144*1024){ idx = u;            dh = Ah; dl = Al; }
    else             { idx = u - 144*1024; dh = Bh; dl = Bl; }
    const int tile = idx >> 10, rem = idx & 1023, ks = rem >> 6, lane = rem & 63;
    const int k0 = ks*32 + (lane >> 4)*8;
    f16x8 hv, lv;
    if (u < 144*1024 || tile < 200){
      const float* src = (u < 144*1024) ? imgs : caps;
      const int m = tile*16 + (lane & 15);
      const float* p = src + (size_t)m*DD + k0;
      #pragma unroll
      for (int j=0;j<8;j++){
        float a = p[j];
        _Float16 h = (_Float16)a;
        hv[j] = h;
        lv[j] = (_Float16)((a - (float)h) * 2048.0f);
      }
    } else {
      const int n = (tile-200)*16 + (lane & 15);          // 0..511
      const float* src = (n < HH) ? (sw1 + n) : (hw1 + n - HH);
      #pragma unroll
      for (int j=0;j<8;j++){
        float a = src[(size_t)(k0+j)*HH];
        _Float16 h = (_Float16)a;
        hv[j] = h;
        lv[j] = (_Float16)((a - (float)h) * 2048.0f);
      }
    }
    *(f16x8*)(dh + (size_t)idx*8) = hv;
    *(f16x8*)(dl + (size_t)idx*8) = lv;
  } else {
    // ---------------- gram body v2: MFMA per caption ----------------
    float* Gt = smem;                       // 64x64 f32
    const int c = blockIdx.x - 1504;        // 0..63
    const int t = threadIdx.x, lane = t & 63, wv = t >> 6;   // 4 waves
    const int wm = wv & 1, wn = wv >> 1;    // 32-row / 32-col tile select
    const float* cbase = caps + (size_t)c*WW*DD;

    f32x16 P, Q;
    #pragma unroll
    for (int e=0;e<16;e++){ P[e]=0.f; Q[e]=0.f; }

    const int r  = lane & 31;
    const int k8 = (lane >> 5)*8;
    const int wA = wm*32 + r;               // A row (word), pad >=50
    const int wB = wn*32 + r;               // B col (word), pad >=50
    const float* pA = cbase + (size_t)wA*DD + k8;
    const float* pB = cbase + (size_t)wB*DD + k8;

    for (int ks=0; ks<32; ks++){
      const int k0 = ks*16;
      float4 a0, a1, b0, b1;
      if (wA < WW){ a0 = *(const float4*)(pA + k0); a1 = *(const float4*)(pA + k0 + 4); }
      else        { a0 = (float4){0,0,0,0}; a1 = a0; }
      if (wB < WW){ b0 = *(const float4*)(pB + k0); b1 = *(const float4*)(pB + k0 + 4); }
      else        { b0 = (float4){0,0,0,0}; b1 = b0; }
      float av[8] = {a0.x,a0.y,a0.z,a0.w,a1.x,a1.y,a1.z,a1.w};
      float bw[8] = {b0.x,b0.y,b0.z,b0.w,b1.x,b1.y,b1.z,b1.w};
      f16x8 ah, al, bh, bl;
      #pragma unroll
      for (int j=0;j<8;j++){
        _Float16 h = (_Float16)av[j];
        ah[j] = h; al[j] = (_Float16)((av[j]-(float)h)*2048.0f);
        _Float16 g = (_Float16)bw[j];
        bh[j] = g; bl[j] = (_Float16)((bw[j]-(float)g)*2048.0f);
      }
      P = __builtin_amdgcn_mfma_f32_32x32x16_f16(ah, bh, P,0,0,0);
      Q = __builtin_amdgcn_mfma_f32_32x32x16_f16(ah, bl, Q,0,0,0);
      Q = __builtin_amdgcn_mfma_f32_32x32x16_f16(al, bh, Q,0,0,0);
    }

    // C layout (HW-verified r4): col=lane&31, row=(reg&3)+8*(reg>>2)+4*(lane>>5)
    const int col = wn*32 + (lane & 31);
    #pragma unroll
    for (int reg=0; reg<16; reg++){
      const int row = wm*32 + (reg&3) + 8*(reg>>2) + 4*(lane>>5);
      float g = P[reg] + Q[reg]*(1.0f/2048.0f);
      Gt[row*64 + col] = g;
      if (row < WW && col < WW)
        G[(size_t)c*WW*WW + row*WW + col] = g;
    }
    __syncthreads();

    // Gfrag build: index-identical to round-3 (per 16-col tile), looped x4.
    #pragma unroll
    for (int tile=0; tile<4; tile++){
      int flat = t*4;
      int ks2 = flat>>9, L=(flat>>3)&63, j0=flat&7;
      const bool ones = (tile==3) && ((L&15)==2);   // frag n == 50
      int n  = tile*16 + (L&15);
      int kk = ks2*32 + ((L>>4)<<3) + j0;
      f16x4 v;
      #pragma unroll
      for (int e=0;e<4;e++)
        v[e] = ones ? (_Float16)1.0f : (_Float16)Gt[n*64 + kk + e];
      *(f16x4*)&Gfrag[(size_t)c*4096 + (tile*2+ks2)*512 + L*8 + j0] = v;
    }
  }
}

// ---------------------------------------------------------------------------
// Combined S-GEMM + gate-GEMM.
//  Round-6 change: XCD-aware supertile swizzle of the sgemm (mb,nb) mapping.
//  Theory: kernel is bound by staged-frag reads (64KB/K-step/CU, ~10 B/cyc
//  effective) with an ~11MB working set scattered over all 8 XCD L2s (4MB
//  each). Swizzle gives each XCD a contiguous logical range ordered by
//  9mb x 5nb supertiles (A 2.25MB + B 1.25MB = 3.6MB <= L2), so re-reads
//  hit own-XCD L2. Bijective (57/57/56x6 chunks, m204 form). Pure index
//  remap -- numerics bit-identical.
// ---------------------------------------------------------------------------
__global__ __launch_bounds__(256, 2) void sgemm_hgate_kernel(
    const _Float16* __restrict__ Ah, const _Float16* __restrict__ Al,
    const _Float16* __restrict__ Bh, const _Float16* __restrict__ Bl,
    float* __restrict__ Sp,
    const float* __restrict__ imgs,
    const float* __restrict__ sb1, const float* __restrict__ hb1,
    const float* __restrict__ sw2, const float* __restrict__ hw2,
    float* __restrict__ drawS, float* __restrict__ drawH,
    float* __restrict__ rnraw)
{
  __shared__ _Float16 lds[2*16384];
  const int t = threadIdx.x, lane = t & 63, wv = t >> 6;

  if (blockIdx.x >= 36){
    // ---------------- sgemm body ----------------
    // XCD swizzle: sg%8 ~ hardware XCD (round-robin model). Each XCD gets a
    // contiguous logical range; logical order = supertiles of 9mb x 5nb.
    const int sg  = blockIdx.x - 36;                    // 0..449
    const int xcd = sg & 7, sidx = sg >> 3;
    const int l   = (xcd < 2 ? xcd*57 : 114 + (xcd-2)*56) + sidx;  // 0..449
    const int st  = l / 45, wi = l - st*45;             // supertile id / within
    const int mbg = st & 1, nbg = st >> 1;              // 2 x 5 supertile grid
    const int mb  = mbg*9 + wi/5;                       // 0..17
    const int nb  = nbg*5 + wi%5;                       // 0..24
    const int wm = wv & 1, wn = wv >> 1;

    f32x4 P[4][4], Q[4][4];
    #pragma unroll
    for (int a=0;a<4;a++)
      #pragma unroll
      for (int b=0;b<4;b++){ P[a][b]=(f32x4){0,0,0,0}; Q[a][b]=(f32x4){0,0,0,0}; }

    const _Float16* sbase = (wv==0)?Ah:(wv==1)?Al:(wv==2)?Bh:Bl;
    const size_t gtb = (size_t)((wv<2)? mb : nb)*8;
    _Float16* buf0 = lds + wv*4096;
    _Float16* buf1 = lds + 16384 + wv*4096;

    // prologue: DMA-stage ks=0 into buf0
    #pragma unroll
    for (int s=0;s<8;s++)
      gl_lds16(sbase + (((gtb+s)*16 + 0)*64 + lane)*8, buf0 + s*512);
    asm volatile("s_waitcnt vmcnt(0)" ::: "memory");
    __syncthreads();

    for (int ks=0; ks<16; ks++){
      if (ks < 15){
        _Float16* nb_ = ((ks+1) & 1) ? buf1 : buf0;
        #pragma unroll
        for (int s=0;s<8;s++)
          gl_lds16(sbase + (((gtb+s)*16 + (ks+1))*64 + lane)*8, nb_ + s*512);
      }

      const _Float16* L = lds + (ks & 1)*16384;
      f16x8 a_h[4], a_l[4], b_h[4], b_l[4];
      #pragma unroll
      for (int x=0;x<4;x++){
        a_h[x] = *(const f16x8*)&L[        (wm*4+x)*512 + lane*8];
        a_l[x] = *(const f16x8*)&L[ 4096 + (wm*4+x)*512 + lane*8];
        b_h[x] = *(const f16x8*)&L[ 8192 + (wn*4+x)*512 + lane*8];
        b_l[x] = *(const f16x8*)&L[12288 + (wn*4+x)*512 + lane*8];
      }
      #pragma unroll
      for (int mi=0;mi<4;mi++)
        #pragma unroll
        for (int ni=0;ni<4;ni++){
          P[mi][ni] = __builtin_amdgcn_mfma_f32_16x16x32_f16(a_h[mi], b_h[ni], P[mi][ni],0,0,0);
          Q[mi][ni] = __builtin_amdgcn_mfma_f32_16x16x32_f16(a_h[mi], b_l[ni], Q[mi][ni],0,0,0);
          Q[mi][ni] = __builtin_amdgcn_mfma_f32_16x16x32_f16(a_l[mi], b_h[ni], Q[mi][ni],0,0,0);
        }

      if (ks < 15)
        asm volatile("s_waitcnt vmcnt(0)" ::: "memory");  // next buf landed
      __syncthreads();
    }

    const int r0 = mb*128 + wm*64 + ((lane>>4)<<2);
    const int c0 = nb*128 + wn*64 + (lane&15);
    size_t pr[16]; size_t pc[4];
    #pragma unroll
    for (int mi=0;mi<4;mi++)
      #pragma unroll
      for (int reg=0;reg<4;reg++){
        unsigned row = (unsigned)(r0 + mi*16 + reg);
        unsigned i = row / 36u, rr_ = row - i*36u;
        pr[mi*4+reg] = (size_t)i*115200u + (size_t)rr_*50u;
      }
    #pragma unroll
    for (int ni=0;ni<4;ni++){
      unsigned col = (unsigned)(c0 + ni*16);
      unsigned cc = col / 50u, w = col - cc*50u;
      pc[ni] = (size_t)cc*1800u + w;
    }
    #pragma unroll
    for (int mi=0;mi<4;mi++)
      #pragma unroll
      for (int ni=0;ni<4;ni++)
        #pragma unroll
        for (int reg=0;reg<4;reg++)
          Sp[pr[mi*4+reg] + pc[ni]] =
              P[mi][ni][reg] + Q[mi][ni][reg]*(1.0f/2048.0f);
    return;
  }

  // ---------------- hgate body ----------------
  const int mb = blockIdx.x >> 1;
  const int br = blockIdx.x & 1;          // 0 = soft, 1 = hard
  const int wm = wv & 1, wn = wv >> 1;

  f32x4 P[4][8];
  #pragma unroll
  for (int a=0;a<4;a++)
    #pragma unroll
    for (int b=0;b<8;b++) P[a][b]=(f32x4){0,0,0,0};

  const _Float16* Bbase = Bh + (size_t)(200 + br*16)*8192;

  // prologue DMA-stage ks=0
  #pragma unroll
  for (int s=0;s<6;s++){
    const int u = wv*6 + s;
    const _Float16* src = (u < 8)
      ? (Ah    + ((size_t)((mb*8 + u)*16 + 0)*64 + lane)*8)
      : (Bbase + ((size_t)((u-8)  *16 + 0)*64 + lane)*8);
    _Float16* dst = (u < 8) ? (lds + u*512) : (lds + 4096 + (u-8)*512);
    gl_lds16(src, dst);
  }
  asm volatile("s_waitcnt vmcnt(0)" ::: "memory");
  __syncthreads();

  for (int ks=0; ks<16; ks++){
    if (ks < 15){
      _Float16* buf = lds + (((ks+1) & 1) ? 16384 : 0);
      #pragma unroll
      for (int s=0;s<6;s++){
        const int u = wv*6 + s;
        const _Float16* src = (u < 8)
          ? (Ah    + ((size_t)((mb*8 + u)*16 + (ks+1))*64 + lane)*8)
          : (Bbase + ((size_t)((u-8)  *16 + (ks+1))*64 + lane)*8);
        _Float16* dst = (u < 8) ? (buf + u*512) : (buf + 4096 + (u-8)*512);
        gl_lds16(src, dst);
      }
    }

    const _Float16* L = lds + (ks & 1)*16384;
    f16x8 a[4], b[8];
    #pragma unroll
    for (int x=0;x<4;x++)
      a[x] = *(const f16x8*)&L[(wm*4+x)*512 + lane*8];
    #pragma unroll
    for (int y=0;y<8;y++)
      b[y] = *(const f16x8*)&L[4096 + (wn*8+y)*512 + lane*8];
    #pragma unroll
    for (int mi=0;mi<4;mi++)
      #pragma unroll
      for (int ni=0;ni<8;ni++)
        P[mi][ni] = __builtin_amdgcn_mfma_f32_16x16x32_f16(a[mi], b[ni], P[mi][ni],0,0,0);

    if (ks < 15)
      asm volatile("s_waitcnt vmcnt(0)" ::: "memory");
    __syncthreads();
  }

  const float* b1 = br ? hb1 : sb1;
  const float* w2 = br ? hw2 : sw2;
  float bvv[8], wvv[8];
  #pragma unroll
  for (int ni=0;ni<8;ni++){
    const int cb = wn*128 + ni*16 + (lane&15);
    bvv[ni] = b1[cb]; wvv[ni] = w2[cb];
  }
  float contrib[16];
  #pragma unroll
  for (int mi=0;mi<4;mi++)
    #pragma unroll
    for (int reg=0;reg<4;reg++){
      float cacc = 0.f;
      #pragma unroll
      for (int ni=0;ni<8;ni++)
        cacc = fmaf(fmaxf(P[mi][ni][reg] + bvv[ni], 0.f), wvv[ni], cacc);
      #pragma unroll
      for (int off=1; off<16; off<<=1) cacc += __shfl_xor(cacc, off, 64);
      contrib[mi*4+reg] = cacc;
    }

  float* red = (float*)lds;
  if ((lane & 15) == 0){
    const int rbase = wm*64 + ((lane>>4)<<2);
    #pragma unroll
    for (int mi=0;mi<4;mi++)
      #pragma unroll
      for (int reg=0;reg<4;reg++)
        red[wn*128 + rbase + mi*16 + reg] = contrib[mi*4+reg];
  }
  __syncthreads();
  if (t < 128){
    float draw = red[t] + red[128 + t];
    (br ? drawH : drawS)[mb*128 + t] = draw;
  }

  if (br == 0){
    const int row = mb*128 + (t >> 1);
    const float* p = imgs + (size_t)row*DD + (t & 1)*256;
    float ss = 0.f;
    #pragma unroll
    for (int q=0;q<64;q++){
      float4 x = ((const float4*)p)[q];
      ss += x.x*x.x + x.y*x.y + x.z*x.z + x.w*x.w;
    }
    ss += __shfl_xor(ss, 1, 64);
    if ((t & 1) == 0) rnraw[row] = ss;
  }
}

// ---------------------------------------------------------------------------
// Epilogue v4 (round-2 verified): single-wave final scalar epilogue.
// ---------------------------------------------------------------------------
__global__ __launch_bounds__(512) void epi_kernel(
    const float* __restrict__ Sp,
    const int* __restrict__ img_lens, const int* __restrict__ cap_lens,
    const float* __restrict__ drawS, const float* __restrict__ drawH,
    const float* __restrict__ rnraw,
    const float* __restrict__ G, const _Float16* __restrict__ Gfrag,
    const float* __restrict__ sb2, const float* __restrict__ hb2,
    float* __restrict__ out)
{
  __shared__ __align__(16) _Float16 sEp[48*72];
  __shared__ __align__(16) _Float16 sE2[48*72];
  __shared__ __align__(16) _Float16 sFp[48*72];
  __shared__ __align__(16) _Float16 sGf[4096];
  __shared__ float sTd[48];
  __shared__ float sTS[48];
  __shared__ float sGd[64];
  __shared__ float sAv[40];
  __shared__ int   sAi[40];

  const int bx = blockIdx.x;
  const int i = bx >> 6, c = bx & 63;
  const int t = threadIdx.x, lane = t & 63;
  const int wv = __builtin_amdgcn_readfirstlane(t >> 6);   // 0..7
  const int cap_len = cap_lens[c];
  const int img_len = img_lens[i];

  ((int4*)sGf)[t] = ((const int4*)(Gfrag + (size_t)c*4096))[t];
  if (t < WW) sGd[t] = G[(size_t)c*WW*WW + t*(WW+1)];

  const int r0 = wv*5;                    // rows r0..r0+4; 36..39 are dummies
  const float* srow = Sp + (size_t)(i*64 + c)*1800u + (size_t)r0*50;
  float sv[5];
  #pragma unroll
  for (int j=0;j<5;j++)
    sv[j] = ((r0+j) < RR && lane < WW) ? srow[j*50 + lane] : 0.f;

  #pragma unroll
  for (int j=0;j<5;j++){
    const int r = r0 + j;
    const float s = sv[j];
    const bool valid = (lane < cap_len);
    float av = wave_max(valid ? s : -INFINITY);
    unsigned long long m = __ballot(valid && (s == av));
    int ai = (int)(__ffsll((long long)m) - 1);
    float e = valid ? __expf(10.0f*(s - av)) : 0.f;
    sEp[r*72 + lane] = (_Float16)e;
    sE2[r*72 + lane] = (_Float16)(e * s);
    if (lane == 0){ sAv[r] = av; sAi[r] = ai; }
  }
  __syncthreads();

  {
    int mi = wv % 3, nt = wv / 3;
    f32x4 acc = (f32x4){0,0,0,0};
    #pragma unroll
    for (int ks=0; ks<2; ks++){
      f16x8 a = *(const f16x8*)&sEp[(mi*16+(lane&15))*72 + ks*32 + ((lane>>4)<<3)];
      f16x8 b = *(const f16x8*)&sGf[(nt*2+ks)*512 + lane*8];
      acc = __builtin_amdgcn_mfma_f32_16x16x32_f16(a, b, acc, 0,0,0);
    }
    #pragma unroll
    for (int reg=0; reg<4; reg++){
      int row = mi*16 + ((lane>>4)<<2) + reg;
      sFp[row*72 + nt*16 + (lane&15)] = (_Float16)acc[reg];
    }
  }
  if (wv < 4){
    int tau = 8 + wv, mi = tau % 3, nt = tau / 3;
    f32x4 acc = (f32x4){0,0,0,0};
    #pragma unroll
    for (int ks=0; ks<2; ks++){
      f16x8 a = *(const f16x8*)&sEp[(mi*16+(lane&15))*72 + ks*32 + ((lane>>4)<<3)];
      f16x8 b = *(const f16x8*)&sGf[(nt*2+ks)*512 + lane*8];
      acc = __builtin_amdgcn_mfma_f32_16x16x32_f16(a, b, acc, 0,0,0);
    }
    #pragma unroll
    for (int reg=0; reg<4; reg++){
      int row = mi*16 + ((lane>>4)<<2) + reg;
      sFp[row*72 + nt*16 + (lane&15)] = (_Float16)acc[reg];
    }
  } else if (wv < 7){
    int mi = wv - 4;
    f32x4 acc = (f32x4){0,0,0,0};
    #pragma unroll
    for (int ks=0; ks<2; ks++){
      f16x8 a = *(const f16x8*)&sE2[(mi*16+(lane&15))*72 + ks*32 + ((lane>>4)<<3)];
      f16x8 b = *(const f16x8*)&sGf[(3*2+ks)*512 + lane*8];
      acc = __builtin_amdgcn_mfma_f32_16x16x32_f16(a, b, acc, 0,0,0);
    }
    if ((lane & 15) == 2){
      #pragma unroll
      for (int reg=0; reg<4; reg++)
        sTS[mi*16 + ((lane>>4)<<2) + reg] = acc[reg];
    }
  }
  __syncthreads();

  if (wv < 3){
    f32x4 acc = (f32x4){0,0,0,0};
    #pragma unroll
    for (int ks=0; ks<2; ks++){
      f16x8 aF = *(const f16x8*)&sFp[(wv*16+(lane&15))*72 + ks*32 + ((lane>>4)<<3)];
      f16x8 bE = *(const f16x8*)&sEp[(wv*16+(lane&15))*72 + ks*32 + ((lane>>4)<<3)];
      acc = __builtin_amdgcn_mfma_f32_16x16x32_f16(aF, bE, acc, 0,0,0);
    }
    #pragma unroll
    for (int reg=0; reg<4; reg++){
      int row = ((lane>>4)<<2) + reg;
      if (row == (lane&15)) sTd[wv*16 + row] = acc[reg];
    }
  }
  __syncthreads();

  // single-wave, one-lane-per-row final epilogue
  if (wv == 0 && lane < RR){
    const int r = lane;
    const int ai = sAi[r];
    const float av = sAv[r];
    float tQ  = sTd[r];
    float tS  = sTS[r];
    float den = (float)sFp[r*72 + 50];
    float dh  = (float)sFp[r*72 + ai];
    float hh  = sGd[ai];
    float hv  = (av > -1.0f) ? 1.f : 0.f;

    const int rg = i*RR + r;
    float sg_ = 1.f/(1.f+__expf(-(drawS[rg] + sb2[0])));
    float hg_ = 1.f/(1.f+__expf(-(drawH[rg] + hb2[0])));
    float tot = sg_ + hg_ + 1e-8f;
    float gs = sg_/tot, gh = hg_/tot;
    float rx = 1.f/fmaxf(sqrtf(rnraw[rg]), 1e-12f);
    float rd = 1.f/den;
    float num = gs*(tS*rd) + hv*gh*av;
    float n2  = gs*gs*(tQ*rd*rd) + hv*(2.f*gs*gh*(dh*rd) + gh*gh*hh);
    float ov  = num * rx / fmaxf(sqrtf(fmaxf(n2, 0.f)), 1e-12f);
    out[((size_t)i*BC + c)*RR + r] = (r < img_len) ? ov : -1.0f;
  }
}

// ---------------------------------------------------------------------------
// Fallback path kernels (round-1 verified), used only if ws too small.
// ---------------------------------------------------------------------------
__global__ __launch_bounds__(256) void gates_kernel(
    const float* __restrict__ imgs,
    const float* __restrict__ sw1, const float* __restrict__ sb1,
    const float* __restrict__ sw2, const float* __restrict__ sb2,
    const float* __restrict__ hw1, const float* __restrict__ hb1,
    const float* __restrict__ hw2, const float* __restrict__ hb2,
    float* __restrict__ sgn, float* __restrict__ hgn, float* __restrict__ rn)
{
  __shared__ __align__(16) float xs[8*DD];
  __shared__ float red[16*256];
  __shared__ float nr[8];
  const int t = threadIdx.x;
  const int row0 = blockIdx.x * 8;
  if (t < 8) nr[t] = 0.f;
  __syncthreads();
  const float4* src = (const float4*)(imgs + (size_t)row0*DD);
  #pragma unroll
  for (int m=0;m<4;m++){
    int n = m*256+t;
    float4 v = src[n];
    ((float4*)xs)[n] = v;
    float ss = v.x*v.x+v.y*v.y+v.z*v.z+v.w*v.w;
    atomicAdd(&nr[n>>7], ss);
  }
  __syncthreads();
  float accS[8]={0,0,0,0,0,0,0,0};
  float accH[8]={0,0,0,0,0,0,0,0};
  for (int k=0;k<DD;k+=4){
    float a0=sw1[(k+0)*HH+t], a1=sw1[(k+1)*HH+t], a2=sw1[(k+2)*HH+t], a3=sw1[(k+3)*HH+t];
    float b0=hw1[(k+0)*HH+t], b1=hw1[(k+1)*HH+t], b2=hw1[(k+2)*HH+t], b3=hw1[(k+3)*HH+t];
    #pragma unroll
    for (int r=0;r<8;r++){
      float4 x = *(const float4*)&xs[r*DD+k];
      accS[r]=fmaf(x.x,a0,accS[r]); accS[r]=fmaf(x.y,a1,accS[r]);
      accS[r]=fmaf(x.z,a2,accS[r]); accS[r]=fmaf(x.w,a3,accS[r]);
      accH[r]=fmaf(x.x,b0,accH[r]); accH[r]=fmaf(x.y,b1,accH[r]);
      accH[r]=fmaf(x.z,b2,accH[r]); accH[r]=fmaf(x.w,b3,accH[r]);
    }
  }
  const float b1s=sb1[t], b1h=hb1[t], w2s=sw2[t], w2h=hw2[t];
  #pragma unroll
  for (int r=0;r<8;r++){
    red[r*256+t]     = w2s * fmaxf(accS[r]+b1s, 0.f);
    red[(8+r)*256+t] = w2h * fmaxf(accH[r]+b1h, 0.f);
  }
  __syncthreads();
  const int wv=t>>6, ln=t&63;
  #pragma unroll
  for (int q=0;q<4;q++){
    int rr_ = wv*4+q;
    float v = red[rr_*256+ln]+red[rr_*256+ln+64]+red[rr_*256+ln+128]+red[rr_*256+ln+192];
    v = wave_sum(v);
    if (ln==0) red[rr_*256] = v;
  }
  __syncthreads();
  if (t<8){
    float os = red[t*256] + sb2[0];
    float oh = red[(8+t)*256] + hb2[0];
    float s = 1.f/(1.f+__expf(-os));
    float h = 1.f/(1.f+__expf(-oh));
    float tot = s+h+1e-8f;
    sgn[row0+t] = s/tot;
    hgn[row0+t] = h/tot;
    rn[row0+t]  = 1.f/fmaxf(sqrtf(nr[t]), 1e-12f);
  }
}

__global__ __launch_bounds__(256) void gram_fb_kernel(
    const float* __restrict__ caps, float* __restrict__ G)
{
  __shared__ __align__(16) float cs[WW*CST];
  const int c    = blockIdx.x >> 2;
  const int tile = blockIdx.x & 3;
  const int w0   = tile*13;
  const int nw   = (tile==3) ? 11 : 13;
  const int t=threadIdx.x, lane=t&63, wv=t>>6;
  const int wl = lane < WW ? lane : WW-1;
  float acc[4]={0.f,0.f,0.f,0.f};
  for (int k0=0;k0<DD;k0+=128){
    __syncthreads();
    for (int n=t;n<WW*32;n+=256){
      int row=n>>5, c4=(n&31)*4;
      *(float4*)&cs[row*CST+c4] = *(const float4*)(caps + ((size_t)c*WW+row)*DD + k0 + c4);
    }
    __syncthreads();
    for (int k=0;k<128;k+=4){
      float4 cv = *(const float4*)&cs[wl*CST+k];
      #pragma unroll
      for (int q=0;q<4;q++){
        int lw = wv + q*4;
        if (lw < nw){
          float4 bv = *(const float4*)&cs[(w0+lw)*CST+k];
          acc[q]=fmaf(bv.x,cv.x,acc[q]); acc[q]=fmaf(bv.y,cv.y,acc[q]);
          acc[q]=fmaf(bv.z,cv.z,acc[q]); acc[q]=fmaf(bv.w,cv.w,acc[q]);
        }
      }
    }
  }
  if (lane < WW){
    #pragma unroll
    for (int q=0;q<4;q++){
      int lw = wv + q*4;
      if (lw < nw) G[(size_t)c*WW*WW + (w0+lw)*WW + lane] = acc[q];
    }
  }
}

__global__ __launch_bounds__(256) void pair_kernel(
    const float* __restrict__ imgs, const float* __restrict__ caps,
    const int* __restrict__ img_lens, const int* __restrict__ cap_lens,
    const float* __restrict__ sgn, const float* __restrict__ hgn,
    const float* __restrict__ rn,
    const float* __restrict__ G, float* __restrict__ out)
{
  __shared__ __align__(16) float smem[WW*CST + 52*52 + RR*52];
  float* cs = smem;
  float* Gs = smem + WW*CST;
  float* As = Gs + 52*52;
  const int bx = blockIdx.x;
  const int i = bx >> 6, c = bx & 63;
  const int t = threadIdx.x, lane = t&63;
  const int wv = __builtin_amdgcn_readfirstlane(t>>6);
  const int wl = lane < WW ? lane : WW-1;
  const int cap_len = cap_lens[c];
  const int img_len = img_lens[i];
  for (int n=t;n<52*52;n+=256){
    int w=n/52, w2=n-w*52;
    Gs[n] = (w<WW && w2<WW) ? G[(size_t)c*WW*WW + w*WW + w2] : 0.f;
  }
  float acc[9]={0,0,0,0,0,0,0,0,0};
  const float* ib = imgs + ((size_t)i*RR + wv*9)*DD;
  for (int k0=0;k0<DD;k0+=128){
    __syncthreads();
    for (int n=t;n<WW*32;n+=256){
      int row=n>>5, c4=(n&31)*4;
      *(float4*)&cs[row*CST+c4] = *(const float4*)(caps + ((size_t)c*WW+row)*DD + k0 + c4);
    }
    __syncthreads();
    for (int k=0;k<128;k+=4){
      float4 cv = *(const float4*)&cs[wl*CST+k];
      #pragma unroll
      for (int j=0;j<9;j++){
        float4 iv = *(const float4*)(ib + j*DD + k0 + k);
        acc[j]=fmaf(iv.x,cv.x,acc[j]); acc[j]=fmaf(iv.y,cv.y,acc[j]);
        acc[j]=fmaf(iv.z,cv.z,acc[j]); acc[j]=fmaf(iv.w,cv.w,acc[j]);
      }
    }
  }
  for (int j=0;j<9;j++){
    const int r = wv*9 + j;
    const float s = acc[j];
    float av; int ai;
    if (lane < cap_len){ av = s;     ai = lane; }
    else if (lane < WW){ av = -1.0f; ai = lane; }
    else               { av = -INFINITY; ai = 64; }
    #pragma unroll
    for (int off=32; off>0; off>>=1){
      float ov = __shfl_xor(av, off, 64);
      int   oi = __shfl_xor(ai, off, 64);
      if (ov > av || (ov == av && oi < ai)){ av = ov; ai = oi; }
    }
    float zv = (lane < cap_len) ? s*10.0f : -INFINITY;
    float zm = wave_max(zv);
    float e  = (lane < cap_len) ? __expf(zv - zm) : 0.f;
    float den = wave_sum(e);
    if (lane < 52) As[r*52 + lane] = (lane < WW) ? e : 0.f;
    float m = 0.f;
    #pragma unroll
    for (int g=0; g<13; g++){
      float4 ab = *(const float4*)&As[r*52 + g*4];
      m = fmaf(ab.x, Gs[(g*4+0)*52+wl], m);
      m = fmaf(ab.y, Gs[(g*4+1)*52+wl], m);
      m = fmaf(ab.z, Gs[(g*4+2)*52+wl], m);
      m = fmaf(ab.w, Gs[(g*4+3)*52+wl], m);
    }
    float tS = wave_sum(e * s);
    float tQ = wave_sum(e * m);
    float dh = __shfl(m, ai, 64);
    float hh = Gs[ai*52 + ai];
    float hv = (ai < cap_len) ? 1.f : 0.f;
    const int rg = i*RR + r;
    float gs = sgn[rg], gh = hgn[rg], rx = rn[rg];
    float rd = 1.f/den;
    float num = gs*(tS*rd) + hv*gh*av;
    float n2  = gs*gs*(tQ*rd*rd) + hv*(2.f*gs*gh*(dh*rd) + gh*gh*hh);
    float ov  = num * rx / fmaxf(sqrtf(fmaxf(n2, 0.f)), 1e-12f);
    if (lane==0) out[((size_t)i*BC + c)*RR + r] = (r < img_len) ? ov : -1.0f;
  }
}

// ---------------------------------------------------------------------------
extern "C" void kernel_launch(void* const* d_in, const int* in_sizes, int n_in,
                              void* d_out, int out_size, void* d_ws, size_t ws_size,
                              hipStream_t stream)
{
  const float* imgs = (const float*)d_in[0];
  const float* caps = (const float*)d_in[1];
  const float* sw1  = (const float*)d_in[2];
  const float* sb1  = (const float*)d_in[3];
  const float* sw2  = (const float*)d_in[4];
  const float* sb2  = (const float*)d_in[5];
  const float* hw1  = (const float*)d_in[6];
  const float* hb1  = (const float*)d_in[7];
  const float* hw2  = (const float*)d_in[8];
  const float* hb2  = (const float*)d_in[9];
  const int* img_lens = (const int*)d_in[10];
  const int* cap_lens = (const int*)d_in[11];

  char* base = (char*)d_ws;
  float*    drawS = (float*)(base + 0);            // raw soft gate sums (2304)
  float*    drawH = (float*)(base + 9216);         // raw hard gate sums (2304)
  float*    rnraw = (float*)(base + 18432);        // raw imgs row sumsq (2304)
  float*    G     = (float*)(base + 27648);        // 640,000  -> 667,648
  _Float16* Gfrag = (_Float16*)(base + 667648);    // 524,288  -> 1,191,936
  _Float16* Ah    = (_Float16*)(base + 1191936);   // 2,359,296 -> 3,551,232
  _Float16* Al    = (_Float16*)(base + 3551232);   // 2,359,296 -> 5,910,528
  _Float16* Bh    = (_Float16*)(base + 5910528);   // 3,801,088 -> 9,711,616
  _Float16* Bl    = (_Float16*)(base + 9711616);   // 3,801,088 -> 13,512,704
  float*    Sp    = (float*)(base + 18231296);     // 29,491,200 -> 47,722,496
  const size_t NEED = 47722496ull;

  float* out = (float*)d_out;

  if (ws_size >= NEED){
    hipLaunchKernelGGL(prepgram_kernel, dim3(1568), dim3(256), 0, stream,
                       imgs, caps, sw1, hw1, Ah, Al, Bh, Bl, G, Gfrag);
    hipLaunchKernelGGL(sgemm_hgate_kernel, dim3(486), dim3(256), 0, stream,
                       Ah, Al, Bh, Bl, Sp,
                       imgs, sb1, hb1, sw2, hw2, drawS, drawH, rnraw);
    hipLaunchKernelGGL(epi_kernel, dim3(BI*BC), dim3(512), 0, stream,
                       Sp, img_lens, cap_lens, drawS, drawH, rnraw,
                       G, Gfrag, sb2, hb2, out);
  } else {
    hipLaunchKernelGGL(gates_kernel, dim3(288), dim3(256), 0, stream,
                       imgs, sw1, sb1, sw2, sb2, hw1, hb1, hw2, hb2,
                       drawS, drawH, rnraw);
    hipLaunchKernelGGL(gram_fb_kernel, dim3(256), dim3(256), 0, stream, caps, G);
    hipLaunchKernelGGL(pair_kernel, dim3(BI*BC), dim3(256), 0, stream,
                       imgs, caps, img_lens, cap_lens, drawS, drawH, rnraw, G, out);
  }
}

// Round 7
// 143.292 us; speedup vs baseline: 1.2439x; 1.0646x over previous
//
#include <hip/hip_runtime.h>
#include <math.h>

#define BI 64
#define RR 36
#define BC 64
#define WW 50
#define DD 512
#define HH 256
#define CST 132

typedef _Float16 f16x8 __attribute__((ext_vector_type(8)));
typedef _Float16 f16x4 __attribute__((ext_vector_type(4)));
typedef float    f32x4 __attribute__((ext_vector_type(4)));
typedef float    f32x16 __attribute__((ext_vector_type(16)));

__device__ __forceinline__ float wave_sum(float v){
  #pragma unroll
  for (int off=32; off>0; off>>=1) v += __shfl_xor(v, off, 64);
  return v;
}
__device__ __forceinline__ float wave_max(float v){
  #pragma unroll
  for (int off=32; off>0; off>>=1) v = fmaxf(v, __shfl_xor(v, off, 64));
  return v;
}

// async global->LDS DMA, 16B per lane (round-3 verified).
__device__ __forceinline__ void gl_lds16(const _Float16* g, _Float16* l){
  __builtin_amdgcn_global_load_lds(
      (const __attribute__((address_space(1))) unsigned int*)g,
      (__attribute__((address_space(3))) unsigned int*)l, 16, 0, 0);
}

// ---------------------------------------------------------------------------
// PrepGram v3 (round-5 verified): prep branch 16-row tiles; gram branch =
// 64 MFMA blocks (32x32x16, layout HW-verified r4), operands from global f32.
// ---------------------------------------------------------------------------
__global__ __launch_bounds__(256) void prepgram_kernel(
    const float* __restrict__ imgs, const float* __restrict__ caps,
    const float* __restrict__ sw1, const float* __restrict__ hw1,
    _Float16* __restrict__ Ah, _Float16* __restrict__ Al,
    _Float16* __restrict__ Bh, _Float16* __restrict__ Bl,
    float* __restrict__ G, _Float16* __restrict__ Gfrag)
{
  __shared__ __align__(16) float smem[64*64];   // gram branch: Gt 64x64 f32
  if (blockIdx.x < 1504){
    int u = blockIdx.x*256 + threadIdx.x;
    _Float16 *dh, *dl; int idx;
    if (u < 144*1024){ idx = u;            dh = Ah; dl = Al; }
    else             { idx = u - 144*1024; dh = Bh; dl = Bl; }
    const int tile = idx >> 10, rem = idx & 1023, ks = rem >> 6, lane = rem & 63;
    const int k0 = ks*32 + (lane >> 4)*8;
    f16x8 hv, lv;
    if (u < 144*1024 || tile < 200){
      const float* src = (u < 144*1024) ? imgs : caps;
      const int m = tile*16 + (lane & 15);
      const float* p = src + (size_t)m*DD + k0;
      #pragma unroll
      for (int j=0;j<8;j++){
        float a = p[j];
        _Float16 h = (_Float16)a;
        hv[j] = h;
        lv[j] = (_Float16)((a - (float)h) * 2048.0f);
      }
    } else {
      const int n = (tile-200)*16 + (lane & 15);          // 0..511
      const float* src = (n < HH) ? (sw1 + n) : (hw1 + n - HH);
      #pragma unroll
      for (int j=0;j<8;j++){
        float a = src[(size_t)(k0+j)*HH];
        _Float16 h = (_Float16)a;
        hv[j] = h;
        lv[j] = (_Float16)((a - (float)h) * 2048.0f);
      }
    }
    *(f16x8*)(dh + (size_t)idx*8) = hv;
    *(f16x8*)(dl + (size_t)idx*8) = lv;
  } else {
    // ---------------- gram body v2: MFMA per caption ----------------
    float* Gt = smem;                       // 64x64 f32
    const int c = blockIdx.x - 1504;        // 0..63
    const int t = threadIdx.x, lane = t & 63, wv = t >> 6;   // 4 waves
    const int wm = wv & 1, wn = wv >> 1;    // 32-row / 32-col tile select
    const float* cbase = caps + (size_t)c*WW*DD;

    f32x16 P, Q;
    #pragma unroll
    for (int e=0;e<16;e++){ P[e]=0.f; Q[e]=0.f; }

    const int r  = lane & 31;
    const int k8 = (lane >> 5)*8;
    const int wA = wm*32 + r;               // A row (word), pad >=50
    const int wB = wn*32 + r;               // B col (word), pad >=50
    const float* pA = cbase + (size_t)wA*DD + k8;
    const float* pB = cbase + (size_t)wB*DD + k8;

    for (int ks=0; ks<32; ks++){
      const int k0 = ks*16;
      float4 a0, a1, b0, b1;
      if (wA < WW){ a0 = *(const float4*)(pA + k0); a1 = *(const float4*)(pA + k0 + 4); }
      else        { a0 = (float4){0,0,0,0}; a1 = a0; }
      if (wB < WW){ b0 = *(const float4*)(pB + k0); b1 = *(const float4*)(pB + k0 + 4); }
      else        { b0 = (float4){0,0,0,0}; b1 = b0; }
      float av[8] = {a0.x,a0.y,a0.z,a0.w,a1.x,a1.y,a1.z,a1.w};
      float bw[8] = {b0.x,b0.y,b0.z,b0.w,b1.x,b1.y,b1.z,b1.w};
      f16x8 ah, al, bh, bl;
      #pragma unroll
      for (int j=0;j<8;j++){
        _Float16 h = (_Float16)av[j];
        ah[j] = h; al[j] = (_Float16)((av[j]-(float)h)*2048.0f);
        _Float16 g = (_Float16)bw[j];
        bh[j] = g; bl[j] = (_Float16)((bw[j]-(float)g)*2048.0f);
      }
      P = __builtin_amdgcn_mfma_f32_32x32x16_f16(ah, bh, P,0,0,0);
      Q = __builtin_amdgcn_mfma_f32_32x32x16_f16(ah, bl, Q,0,0,0);
      Q = __builtin_amdgcn_mfma_f32_32x32x16_f16(al, bh, Q,0,0,0);
    }

    // C layout (HW-verified r4): col=lane&31, row=(reg&3)+8*(reg>>2)+4*(lane>>5)
    const int col = wn*32 + (lane & 31);
    #pragma unroll
    for (int reg=0; reg<16; reg++){
      const int row = wm*32 + (reg&3) + 8*(reg>>2) + 4*(lane>>5);
      float g = P[reg] + Q[reg]*(1.0f/2048.0f);
      Gt[row*64 + col] = g;
      if (row < WW && col < WW)
        G[(size_t)c*WW*WW + row*WW + col] = g;
    }
    __syncthreads();

    // Gfrag build: index-identical to round-3 (per 16-col tile), looped x4.
    #pragma unroll
    for (int tile=0; tile<4; tile++){
      int flat = t*4;
      int ks2 = flat>>9, L=(flat>>3)&63, j0=flat&7;
      const bool ones = (tile==3) && ((L&15)==2);   // frag n == 50
      int n  = tile*16 + (L&15);
      int kk = ks2*32 + ((L>>4)<<3) + j0;
      f16x4 v;
      #pragma unroll
      for (int e=0;e<4;e++)
        v[e] = ones ? (_Float16)1.0f : (_Float16)Gt[n*64 + kk + e];
      *(f16x4*)&Gfrag[(size_t)c*4096 + (tile*2+ks2)*512 + L*8 + j0] = v;
    }
  }
}

// ---------------------------------------------------------------------------
// Combined S-GEMM + gate-GEMM (round-6 verified: DMA staging + XCD-aware
// supertile swizzle). Unchanged this round.
// ---------------------------------------------------------------------------
__global__ __launch_bounds__(256, 2) void sgemm_hgate_kernel(
    const _Float16* __restrict__ Ah, const _Float16* __restrict__ Al,
    const _Float16* __restrict__ Bh, const _Float16* __restrict__ Bl,
    float* __restrict__ Sp,
    const float* __restrict__ imgs,
    const float* __restrict__ sb1, const float* __restrict__ hb1,
    const float* __restrict__ sw2, const float* __restrict__ hw2,
    float* __restrict__ drawS, float* __restrict__ drawH,
    float* __restrict__ rnraw)
{
  __shared__ _Float16 lds[2*16384];
  const int t = threadIdx.x, lane = t & 63, wv = t >> 6;

  if (blockIdx.x >= 36){
    // ---------------- sgemm body ----------------
    const int sg  = blockIdx.x - 36;                    // 0..449
    const int xcd = sg & 7, sidx = sg >> 3;
    const int l   = (xcd < 2 ? xcd*57 : 114 + (xcd-2)*56) + sidx;  // 0..449
    const int st  = l / 45, wi = l - st*45;             // supertile id / within
    const int mbg = st & 1, nbg = st >> 1;              // 2 x 5 supertile grid
    const int mb  = mbg*9 + wi/5;                       // 0..17
    const int nb  = nbg*5 + wi%5;                       // 0..24
    const int wm = wv & 1, wn = wv >> 1;

    f32x4 P[4][4], Q[4][4];
    #pragma unroll
    for (int a=0;a<4;a++)
      #pragma unroll
      for (int b=0;b<4;b++){ P[a][b]=(f32x4){0,0,0,0}; Q[a][b]=(f32x4){0,0,0,0}; }

    const _Float16* sbase = (wv==0)?Ah:(wv==1)?Al:(wv==2)?Bh:Bl;
    const size_t gtb = (size_t)((wv<2)? mb : nb)*8;
    _Float16* buf0 = lds + wv*4096;
    _Float16* buf1 = lds + 16384 + wv*4096;

    // prologue: DMA-stage ks=0 into buf0
    #pragma unroll
    for (int s=0;s<8;s++)
      gl_lds16(sbase + (((gtb+s)*16 + 0)*64 + lane)*8, buf0 + s*512);
    asm volatile("s_waitcnt vmcnt(0)" ::: "memory");
    __syncthreads();

    for (int ks=0; ks<16; ks++){
      if (ks < 15){
        _Float16* nb_ = ((ks+1) & 1) ? buf1 : buf0;
        #pragma unroll
        for (int s=0;s<8;s++)
          gl_lds16(sbase + (((gtb+s)*16 + (ks+1))*64 + lane)*8, nb_ + s*512);
      }

      const _Float16* L = lds + (ks & 1)*16384;
      f16x8 a_h[4], a_l[4], b_h[4], b_l[4];
      #pragma unroll
      for (int x=0;x<4;x++){
        a_h[x] = *(const f16x8*)&L[        (wm*4+x)*512 + lane*8];
        a_l[x] = *(const f16x8*)&L[ 4096 + (wm*4+x)*512 + lane*8];
        b_h[x] = *(const f16x8*)&L[ 8192 + (wn*4+x)*512 + lane*8];
        b_l[x] = *(const f16x8*)&L[12288 + (wn*4+x)*512 + lane*8];
      }
      #pragma unroll
      for (int mi=0;mi<4;mi++)
        #pragma unroll
        for (int ni=0;ni<4;ni++){
          P[mi][ni] = __builtin_amdgcn_mfma_f32_16x16x32_f16(a_h[mi], b_h[ni], P[mi][ni],0,0,0);
          Q[mi][ni] = __builtin_amdgcn_mfma_f32_16x16x32_f16(a_h[mi], b_l[ni], Q[mi][ni],0,0,0);
          Q[mi][ni] = __builtin_amdgcn_mfma_f32_16x16x32_f16(a_l[mi], b_h[ni], Q[mi][ni],0,0,0);
        }

      if (ks < 15)
        asm volatile("s_waitcnt vmcnt(0)" ::: "memory");  // next buf landed
      __syncthreads();
    }

    const int r0 = mb*128 + wm*64 + ((lane>>4)<<2);
    const int c0 = nb*128 + wn*64 + (lane&15);
    size_t pr[16]; size_t pc[4];
    #pragma unroll
    for (int mi=0;mi<4;mi++)
      #pragma unroll
      for (int reg=0;reg<4;reg++){
        unsigned row = (unsigned)(r0 + mi*16 + reg);
        unsigned i = row / 36u, rr_ = row - i*36u;
        pr[mi*4+reg] = (size_t)i*115200u + (size_t)rr_*50u;
      }
    #pragma unroll
    for (int ni=0;ni<4;ni++){
      unsigned col = (unsigned)(c0 + ni*16);
      unsigned cc = col / 50u, w = col - cc*50u;
      pc[ni] = (size_t)cc*1800u + w;
    }
    #pragma unroll
    for (int mi=0;mi<4;mi++)
      #pragma unroll
      for (int ni=0;ni<4;ni++)
        #pragma unroll
        for (int reg=0;reg<4;reg++)
          Sp[pr[mi*4+reg] + pc[ni]] =
              P[mi][ni][reg] + Q[mi][ni][reg]*(1.0f/2048.0f);
    return;
  }

  // ---------------- hgate body ----------------
  const int mb = blockIdx.x >> 1;
  const int br = blockIdx.x & 1;          // 0 = soft, 1 = hard
  const int wm = wv & 1, wn = wv >> 1;

  f32x4 P[4][8];
  #pragma unroll
  for (int a=0;a<4;a++)
    #pragma unroll
    for (int b=0;b<8;b++) P[a][b]=(f32x4){0,0,0,0};

  const _Float16* Bbase = Bh + (size_t)(200 + br*16)*8192;

  // prologue DMA-stage ks=0
  #pragma unroll
  for (int s=0;s<6;s++){
    const int u = wv*6 + s;
    const _Float16* src = (u < 8)
      ? (Ah    + ((size_t)((mb*8 + u)*16 + 0)*64 + lane)*8)
      : (Bbase + ((size_t)((u-8)  *16 + 0)*64 + lane)*8);
    _Float16* dst = (u < 8) ? (lds + u*512) : (lds + 4096 + (u-8)*512);
    gl_lds16(src, dst);
  }
  asm volatile("s_waitcnt vmcnt(0)" ::: "memory");
  __syncthreads();

  for (int ks=0; ks<16; ks++){
    if (ks < 15){
      _Float16* buf = lds + (((ks+1) & 1) ? 16384 : 0);
      #pragma unroll
      for (int s=0;s<6;s++){
        const int u = wv*6 + s;
        const _Float16* src = (u < 8)
          ? (Ah    + ((size_t)((mb*8 + u)*16 + (ks+1))*64 + lane)*8)
          : (Bbase + ((size_t)((u-8)  *16 + (ks+1))*64 + lane)*8);
        _Float16* dst = (u < 8) ? (buf + u*512) : (buf + 4096 + (u-8)*512);
        gl_lds16(src, dst);
      }
    }

    const _Float16* L = lds + (ks & 1)*16384;
    f16x8 a[4], b[8];
    #pragma unroll
    for (int x=0;x<4;x++)
      a[x] = *(const f16x8*)&L[(wm*4+x)*512 + lane*8];
    #pragma unroll
    for (int y=0;y<8;y++)
      b[y] = *(const f16x8*)&L[4096 + (wn*8+y)*512 + lane*8];
    #pragma unroll
    for (int mi=0;mi<4;mi++)
      #pragma unroll
      for (int ni=0;ni<8;ni++)
        P[mi][ni] = __builtin_amdgcn_mfma_f32_16x16x32_f16(a[mi], b[ni], P[mi][ni],0,0,0);

    if (ks < 15)
      asm volatile("s_waitcnt vmcnt(0)" ::: "memory");
    __syncthreads();
  }

  const float* b1 = br ? hb1 : sb1;
  const float* w2 = br ? hw2 : sw2;
  float bvv[8], wvv[8];
  #pragma unroll
  for (int ni=0;ni<8;ni++){
    const int cb = wn*128 + ni*16 + (lane&15);
    bvv[ni] = b1[cb]; wvv[ni] = w2[cb];
  }
  float contrib[16];
  #pragma unroll
  for (int mi=0;mi<4;mi++)
    #pragma unroll
    for (int reg=0;reg<4;reg++){
      float cacc = 0.f;
      #pragma unroll
      for (int ni=0;ni<8;ni++)
        cacc = fmaf(fmaxf(P[mi][ni][reg] + bvv[ni], 0.f), wvv[ni], cacc);
      #pragma unroll
      for (int off=1; off<16; off<<=1) cacc += __shfl_xor(cacc, off, 64);
      contrib[mi*4+reg] = cacc;
    }

  float* red = (float*)lds;
  if ((lane & 15) == 0){
    const int rbase = wm*64 + ((lane>>4)<<2);
    #pragma unroll
    for (int mi=0;mi<4;mi++)
      #pragma unroll
      for (int reg=0;reg<4;reg++)
        red[wn*128 + rbase + mi*16 + reg] = contrib[mi*4+reg];
  }
  __syncthreads();
  if (t < 128){
    float draw = red[t] + red[128 + t];
    (br ? drawH : drawS)[mb*128 + t] = draw;
  }

  if (br == 0){
    const int row = mb*128 + (t >> 1);
    const float* p = imgs + (size_t)row*DD + (t & 1)*256;
    float ss = 0.f;
    #pragma unroll
    for (int q=0;q<64;q++){
      float4 x = ((const float4*)p)[q];
      ss += x.x*x.x + x.y*x.y + x.z*x.z + x.w*x.w;
    }
    ss += __shfl_xor(ss, 1, 64);
    if ((t & 1) == 0) rnraw[row] = ss;
  }
}

// ---------------------------------------------------------------------------
// Epilogue v5 (round-7): ONE WAVE = ONE (i,c) PAIR, in-register.
//  Old epi was DS-pipe bound (~800 wave-DS-ops/pair: shfl-heavy softmax,
//  scalar u16 LDS staging, 3 barriers, 8-wave sharing). v5: S loaded straight
//  into MFMA B-frag layout from global; row stats via 2 shfl_xor (lanes
//  sharing a row differ only in bits 4-5); F^T = G @ E^T with Gfrag read as
//  the A-operand directly from global (G symmetric; stored B-frag formula ==
//  A-frag formula); F^T spilled once to a per-wave LDS scratch so tQ and dh
//  are simple reads. No barriers, no cross-wave traffic, ~55 DS/pair.
//  Rounding points (e->f16, e*s->f16, F->f16, den->f16) match epi v4 exactly.
// ---------------------------------------------------------------------------
__global__ __launch_bounds__(256) void epi_kernel(
    const float* __restrict__ Sp,
    const int* __restrict__ img_lens, const int* __restrict__ cap_lens,
    const float* __restrict__ drawS, const float* __restrict__ drawH,
    const float* __restrict__ rnraw,
    const float* __restrict__ G, const _Float16* __restrict__ Gfrag,
    const float* __restrict__ sb2, const float* __restrict__ hb2,
    float* __restrict__ out)
{
  __shared__ __align__(16) _Float16 FT[4][48*72];   // per-wave F scratch
  const int t = threadIdx.x, lane = t & 63;
  const int wv = __builtin_amdgcn_readfirstlane(t >> 6);   // 0..3
  const int pair = blockIdx.x*4 + wv;                      // 0..4095
  const int i = pair >> 6, c = pair & 63;
  const int l = lane & 15, g = lane >> 4;
  const int cap_len = cap_lens[c];
  const int img_len = img_lens[i];

  // G A-frags (== stored B-frags; G symmetric): 8 x int4 per lane
  int4 gf[8];
  #pragma unroll
  for (int q=0;q<8;q++)
    gf[q] = ((const int4*)(Gfrag + (size_t)c*4096))[q*64 + lane];

  // S loads into B-frag layout: frag (nt,ks): row rr=16nt+l, w0=32ks+8g.
  // 8-byte-aligned float2 loads (row stride 50 f32 = 200 B). Over-reads
  // within the workspace are masked in registers.
  const float* sbp = Sp + (size_t)i*115200 + (size_t)c*1800;
  float sv[3][16];
  #pragma unroll
  for (int nt=0;nt<3;nt++)
    #pragma unroll
    for (int ks=0;ks<2;ks++){
      const float* p = sbp + (nt*16+l)*50 + ks*32 + g*8;
      #pragma unroll
      for (int h=0;h<4;h++){
        float2 v2 = *(const float2*)(p + h*2);
        sv[nt][ks*8 + h*2]     = v2.x;
        sv[nt][ks*8 + h*2 + 1] = v2.y;
      }
    }

  // per-row stats + e16 fragments
  float avA[3]; int aiA[3]; float denA[3], tSA[3];
  f16x8 e16[3][2];
  #pragma unroll
  for (int nt=0;nt<3;nt++){
    float best = -INFINITY; int bw = 64;
    #pragma unroll
    for (int j=0;j<16;j++){
      int w = (j>>3)*32 + g*8 + (j&7);
      if (w < cap_len){
        float s = sv[nt][j];
        if (s > best){ best = s; bw = w; }
      }
    }
    #pragma unroll
    for (int off=16; off<64; off<<=1){
      float ov = __shfl_xor(best, off, 64);
      int   ow = __shfl_xor(bw,   off, 64);
      if (ov > best || (ov == best && ow < bw)){ best = ov; bw = ow; }
    }
    avA[nt] = best; aiA[nt] = (bw < 64) ? bw : 0;

    float dsum = 0.f, tsum = 0.f;
    #pragma unroll
    for (int ks=0;ks<2;ks++)
      #pragma unroll
      for (int j=0;j<8;j++){
        int w = ks*32 + g*8 + j;
        float s = sv[nt][ks*8+j];
        float e = (w < cap_len) ? __expf(10.0f*(s - best)) : 0.f;
        _Float16 eh = (_Float16)e;
        e16[nt][ks][j] = eh;
        dsum += (float)eh;
        tsum += (float)(_Float16)(e * s);
      }
    dsum += __shfl_xor(dsum,16,64); dsum += __shfl_xor(dsum,32,64);
    tsum += __shfl_xor(tsum,16,64); tsum += __shfl_xor(tsum,32,64);
    denA[nt] = dsum; tSA[nt] = tsum;
  }

  // F^T = G @ E^T  (C-layout out: col=rr_local=l, row=w'=16mt+4g+reg)
  _Float16* ft = &FT[wv][0];
  #pragma unroll
  for (int mt=0;mt<4;mt++)
    #pragma unroll
    for (int nt=0;nt<3;nt++){
      f32x4 acc = (f32x4){0,0,0,0};
      #pragma unroll
      for (int ks=0;ks<2;ks++){
        f16x8 ga = *(const f16x8*)&gf[mt*2+ks];
        acc = __builtin_amdgcn_mfma_f32_16x16x32_f16(ga, e16[nt][ks], acc,0,0,0);
      }
      f16x4 fv;
      #pragma unroll
      for (int r2=0;r2<4;r2++) fv[r2] = (_Float16)acc[r2];
      *(f16x4*)&ft[(nt*16+l)*72 + mt*16 + g*4] = fv;   // F[rr][w'] (f16)
    }

  // tQ[r] = sum_w e16[r,w] * F16[r,w]  (read F back in e's own layout)
  float tQA[3];
  #pragma unroll
  for (int nt=0;nt<3;nt++){
    float q = 0.f;
    #pragma unroll
    for (int ks=0;ks<2;ks++){
      f16x8 fv = *(const f16x8*)&ft[(nt*16+l)*72 + ks*32 + g*8];
      #pragma unroll
      for (int j=0;j<8;j++)
        q += (float)e16[nt][ks][j] * (float)fv[j];
    }
    q += __shfl_xor(q,16,64); q += __shfl_xor(q,32,64);
    tQA[nt] = q;
  }

  // final per-row scalar epilogue on g==0 lanes (rows rr = 16nt + l)
  if (lane < 16){
    const float sb2v = sb2[0], hb2v = hb2[0];
    #pragma unroll
    for (int nt=0;nt<3;nt++){
      const int rr = nt*16 + lane;
      if (rr < RR){
        const int ai = aiA[nt];
        const float av = avA[nt];
        float dh = (float)ft[rr*72 + ai];
        float hh = G[(size_t)c*WW*WW + ai*(WW+1)];
        float hv = (av > -1.0f) ? 1.f : 0.f;
        const int rg = i*RR + rr;
        float sg_ = 1.f/(1.f+__expf(-(drawS[rg] + sb2v)));
        float hg_ = 1.f/(1.f+__expf(-(drawH[rg] + hb2v)));
        float tot = sg_ + hg_ + 1e-8f;
        float gs = sg_/tot, gh = hg_/tot;
        float rx = 1.f/fmaxf(sqrtf(rnraw[rg]), 1e-12f);
        float dn = (float)(_Float16)denA[nt];
        float rd = 1.f/dn;
        float num = gs*(tSA[nt]*rd) + hv*gh*av;
        float n2  = gs*gs*(tQA[nt]*rd*rd) + hv*(2.f*gs*gh*(dh*rd) + gh*gh*hh);
        float ov  = num * rx / fmaxf(sqrtf(fmaxf(n2, 0.f)), 1e-12f);
        out[((size_t)i*BC + c)*RR + rr] = (rr < img_len) ? ov : -1.0f;
      }
    }
  }
}

// ---------------------------------------------------------------------------
// Fallback path kernels (round-1 verified), used only if ws too small.
// ---------------------------------------------------------------------------
__global__ __launch_bounds__(256) void gates_kernel(
    const float* __restrict__ imgs,
    const float* __restrict__ sw1, const float* __restrict__ sb1,
    const float* __restrict__ sw2, const float* __restrict__ sb2,
    const float* __restrict__ hw1, const float* __restrict__ hb1,
    const float* __restrict__ hw2, const float* __restrict__ hb2,
    float* __restrict__ sgn, float* __restrict__ hgn, float* __restrict__ rn)
{
  __shared__ __align__(16) float xs[8*DD];
  __shared__ float red[16*256];
  __shared__ float nr[8];
  const int t = threadIdx.x;
  const int row0 = blockIdx.x * 8;
  if (t < 8) nr[t] = 0.f;
  __syncthreads();
  const float4* src = (const float4*)(imgs + (size_t)row0*DD);
  #pragma unroll
  for (int m=0;m<4;m++){
    int n = m*256+t;
    float4 v = src[n];
    ((float4*)xs)[n] = v;
    float ss = v.x*v.x+v.y*v.y+v.z*v.z+v.w*v.w;
    atomicAdd(&nr[n>>7], ss);
  }
  __syncthreads();
  float accS[8]={0,0,0,0,0,0,0,0};
  float accH[8]={0,0,0,0,0,0,0,0};
  for (int k=0;k<DD;k+=4){
    float a0=sw1[(k+0)*HH+t], a1=sw1[(k+1)*HH+t], a2=sw1[(k+2)*HH+t], a3=sw1[(k+3)*HH+t];
    float b0=hw1[(k+0)*HH+t], b1=hw1[(k+1)*HH+t], b2=hw1[(k+2)*HH+t], b3=hw1[(k+3)*HH+t];
    #pragma unroll
    for (int r=0;r<8;r++){
      float4 x = *(const float4*)&xs[r*DD+k];
      accS[r]=fmaf(x.x,a0,accS[r]); accS[r]=fmaf(x.y,a1,accS[r]);
      accS[r]=fmaf(x.z,a2,accS[r]); accS[r]=fmaf(x.w,a3,accS[r]);
      accH[r]=fmaf(x.x,b0,accH[r]); accH[r]=fmaf(x.y,b1,accH[r]);
      accH[r]=fmaf(x.z,b2,accH[r]); accH[r]=fmaf(x.w,b3,accH[r]);
    }
  }
  const float b1s=sb1[t], b1h=hb1[t], w2s=sw2[t], w2h=hw2[t];
  #pragma unroll
  for (int r=0;r<8;r++){
    red[r*256+t]     = w2s * fmaxf(accS[r]+b1s, 0.f);
    red[(8+r)*256+t] = w2h * fmaxf(accH[r]+b1h, 0.f);
  }
  __syncthreads();
  const int wv=t>>6, ln=t&63;
  #pragma unroll
  for (int q=0;q<4;q++){
    int rr_ = wv*4+q;
    float v = red[rr_*256+ln]+red[rr_*256+ln+64]+red[rr_*256+ln+128]+red[rr_*256+ln+192];
    v = wave_sum(v);
    if (ln==0) red[rr_*256] = v;
  }
  __syncthreads();
  if (t<8){
    float os = red[t*256] + sb2[0];
    float oh = red[(8+t)*256] + hb2[0];
    float s = 1.f/(1.f+__expf(-os));
    float h = 1.f/(1.f+__expf(-oh));
    float tot = s+h+1e-8f;
    sgn[row0+t] = s/tot;
    hgn[row0+t] = h/tot;
    rn[row0+t]  = 1.f/fmaxf(sqrtf(nr[t]), 1e-12f);
  }
}

__global__ __launch_bounds__(256) void gram_fb_kernel(
    const float* __restrict__ caps, float* __restrict__ G)
{
  __shared__ __align__(16) float cs[WW*CST];
  const int c    = blockIdx.x >> 2;
  const int tile = blockIdx.x & 3;
  const int w0   = tile*13;
  const int nw   = (tile==3) ? 11 : 13;
  const int t=threadIdx.x, lane=t&63, wv=t>>6;
  const int wl = lane < WW ? lane : WW-1;
  float acc[4]={0.f,0.f,0.f,0.f};
  for (int k0=0;k0<DD;k0+=128){
    __syncthreads();
    for (int n=t;n<WW*32;n+=256){
      int row=n>>5, c4=(n&31)*4;
      *(float4*)&cs[row*CST+c4] = *(const float4*)(caps + ((size_t)c*WW+row)*DD + k0 + c4);
    }
    __syncthreads();
    for (int k=0;k<128;k+=4){
      float4 cv = *(const float4*)&cs[wl*CST+k];
      #pragma unroll
      for (int q=0;q<4;q++){
        int lw = wv + q*4;
        if (lw < nw){
          float4 bv = *(const float4*)&cs[(w0+lw)*CST+k];
          acc[q]=fmaf(bv.x,cv.x,acc[q]); acc[q]=fmaf(bv.y,cv.y,acc[q]);
          acc[q]=fmaf(bv.z,cv.z,acc[q]); acc[q]=fmaf(bv.w,cv.w,acc[q]);
        }
      }
    }
  }
  if (lane < WW){
    #pragma unroll
    for (int q=0;q<4;q++){
      int lw = wv + q*4;
      if (lw < nw) G[(size_t)c*WW*WW + (w0+lw)*WW + lane] = acc[q];
    }
  }
}

__global__ __launch_bounds__(256) void pair_kernel(
    const float* __restrict__ imgs, const float* __restrict__ caps,
    const int* __restrict__ img_lens, const int* __restrict__ cap_lens,
    const float* __restrict__ sgn, const float* __restrict__ hgn,
    const float* __restrict__ rn,
    const float* __restrict__ G, float* __restrict__ out)
{
  __shared__ __align__(16) float smem[WW*CST + 52*52 + RR*52];
  float* cs = smem;
  float* Gs = smem + WW*CST;
  float* As = Gs + 52*52;
  const int bx = blockIdx.x;
  const int i = bx >> 6, c = bx & 63;
  const int t = threadIdx.x, lane = t&63;
  const int wv = __builtin_amdgcn_readfirstlane(t>>6);
  const int wl = lane < WW ? lane : WW-1;
  const int cap_len = cap_lens[c];
  const int img_len = img_lens[i];
  for (int n=t;n<52*52;n+=256){
    int w=n/52, w2=n-w*52;
    Gs[n] = (w<WW && w2<WW) ? G[(size_t)c*WW*WW + w*WW + w2] : 0.f;
  }
  float acc[9]={0,0,0,0,0,0,0,0,0};
  const float* ib = imgs + ((size_t)i*RR + wv*9)*DD;
  for (int k0=0;k0<DD;k0+=128){
    __syncthreads();
    for (int n=t;n<WW*32;n+=256){
      int row=n>>5, c4=(n&31)*4;
      *(float4*)&cs[row*CST+c4] = *(const float4*)(caps + ((size_t)c*WW+row)*DD + k0 + c4);
    }
    __syncthreads();
    for (int k=0;k<128;k+=4){
      float4 cv = *(const float4*)&cs[wl*CST+k];
      #pragma unroll
      for (int j=0;j<9;j++){
        float4 iv = *(const float4*)(ib + j*DD + k0 + k);
        acc[j]=fmaf(iv.x,cv.x,acc[j]); acc[j]=fmaf(iv.y,cv.y,acc[j]);
        acc[j]=fmaf(iv.z,cv.z,acc[j]); acc[j]=fmaf(iv.w,cv.w,acc[j]);
      }
    }
  }
  for (int j=0;j<9;j++){
    const int r = wv*9 + j;
    const float s = acc[j];
    float av; int ai;
    if (lane < cap_len){ av = s;     ai = lane; }
    else if (lane < WW){ av = -1.0f; ai = lane; }
    else               { av = -INFINITY; ai = 64; }
    #pragma unroll
    for (int off=32; off>0; off>>=1){
      float ov = __shfl_xor(av, off, 64);
      int   oi = __shfl_xor(ai, off, 64);
      if (ov > av || (ov == av && oi < ai)){ av = ov; ai = oi; }
    }
    float zv = (lane < cap_len) ? s*10.0f : -INFINITY;
    float zm = wave_max(zv);
    float e  = (lane < cap_len) ? __expf(zv - zm) : 0.f;
    float den = wave_sum(e);
    if (lane < 52) As[r*52 + lane] = (lane < WW) ? e : 0.f;
    float m = 0.f;
    #pragma unroll
    for (int g=0; g<13; g++){
      float4 ab = *(const float4*)&As[r*52 + g*4];
      m = fmaf(ab.x, Gs[(g*4+0)*52+wl], m);
      m = fmaf(ab.y, Gs[(g*4+1)*52+wl], m);
      m = fmaf(ab.z, Gs[(g*4+2)*52+wl], m);
      m = fmaf(ab.w, Gs[(g*4+3)*52+wl], m);
    }
    float tS = wave_sum(e * s);
    float tQ = wave_sum(e * m);
    float dh = __shfl(m, ai, 64);
    float hh = Gs[ai*52 + ai];
    float hv = (ai < cap_len) ? 1.f : 0.f;
    const int rg = i*RR + r;
    float gs = sgn[rg], gh = hgn[rg], rx = rn[rg];
    float rd = 1.f/den;
    float num = gs*(tS*rd) + hv*gh*av;
    float n2  = gs*gs*(tQ*rd*rd) + hv*(2.f*gs*gh*(dh*rd) + gh*gh*hh);
    float ov  = num * rx / fmaxf(sqrtf(fmaxf(n2, 0.f)), 1e-12f);
    if (lane==0) out[((size_t)i*BC + c)*RR + r] = (r < img_len) ? ov : -1.0f;
  }
}

// ---------------------------------------------------------------------------
extern "C" void kernel_launch(void* const* d_in, const int* in_sizes, int n_in,
                              void* d_out, int out_size, void* d_ws, size_t ws_size,
                              hipStream_t stream)
{
  const float* imgs = (const float*)d_in[0];
  const float* caps = (const float*)d_in[1];
  const float* sw1  = (const float*)d_in[2];
  const float* sb1  = (const float*)d_in[3];
  const float* sw2  = (const float*)d_in[4];
  const float* sb2  = (const float*)d_in[5];
  const float* hw1  = (const float*)d_in[6];
  const float* hb1  = (const float*)d_in[7];
  const float* hw2  = (const float*)d_in[8];
  const float* hb2  = (const float*)d_in[9];
  const int* img_lens = (const int*)d_in[10];
  const int* cap_lens = (const int*)d_in[11];

  char* base = (char*)d_ws;
  float*    drawS = (float*)(base + 0);            // raw soft gate sums (2304)
  float*    drawH = (float*)(base + 9216);         // raw hard gate sums (2304)
  float*    rnraw = (float*)(base + 18432);        // raw imgs row sumsq (2304)
  float*    G     = (float*)(base + 27648);        // 640,000  -> 667,648
  _Float16* Gfrag = (_Float16*)(base + 667648);    // 524,288  -> 1,191,936
  _Float16* Ah    = (_Float16*)(base + 1191936);   // 2,359,296 -> 3,551,232
  _Float16* Al    = (_Float16*)(base + 3551232);   // 2,359,296 -> 5,910,528
  _Float16* Bh    = (_Float16*)(base + 5910528);   // 3,801,088 -> 9,711,616
  _Float16* Bl    = (_Float16*)(base + 9711616);   // 3,801,088 -> 13,512,704
  float*    Sp    = (float*)(base + 18231296);     // 29,491,200 -> 47,722,496
  // +4KB slack: epi v5's vectorized S loads may over-read past Sp's end
  // (masked in registers); keep the tail inside the workspace.
  const size_t NEED = 47726592ull;

  float* out = (float*)d_out;

  if (ws_size >= NEED){
    hipLaunchKernelGGL(prepgram_kernel, dim3(1568), dim3(256), 0, stream,
                       imgs, caps, sw1, hw1, Ah, Al, Bh, Bl, G, Gfrag);
    hipLaunchKernelGGL(sgemm_hgate_kernel, dim3(486), dim3(256), 0, stream,
                       Ah, Al, Bh, Bl, Sp,
                       imgs, sb1, hb1, sw2, hw2, drawS, drawH, rnraw);
    hipLaunchKernelGGL(epi_kernel, dim3(1024), dim3(256), 0, stream,
                       Sp, img_lens, cap_lens, drawS, drawH, rnraw,
                       G, Gfrag, sb2, hb2, out);
  } else {
    hipLaunchKernelGGL(gates_kernel, dim3(288), dim3(256), 0, stream,
                       imgs, sw1, sb1, sw2, sb2, hw1, hb1, hw2, hb2,
                       drawS, drawH, rnraw);
    hipLaunchKernelGGL(gram_fb_kernel, dim3(256), dim3(256), 0, stream, caps, G);
    hipLaunchKernelGGL(pair_kernel, dim3(BI*BC), dim3(256), 0, stream,
                       imgs, caps, img_lens, cap_lens, drawS, drawH, rnraw, G, out);
  }
}